// Round 6
// baseline (277.261 us; speedup 1.0000x reference)
//
#include <hip/hip_runtime.h>
#include <stdint.h>

typedef float f32x4 __attribute__((ext_vector_type(4)));
typedef __bf16 bf16x8 __attribute__((ext_vector_type(8)));

#define DEV __device__ __forceinline__

DEV unsigned short f2bf(float f) {
  unsigned u = __float_as_uint(f);
  u += 0x7FFFu + ((u >> 16) & 1u);   // round-to-nearest-even
  return (unsigned short)(u >> 16);
}

DEV float exp2_(float x) {
#if __has_builtin(__builtin_amdgcn_exp2f)
  return __builtin_amdgcn_exp2f(x);   // raw v_exp_f32; args in [-60,0] => normal range
#else
  return exp2f(x);
#endif
}

// pack two f32 -> one u32 of 2 bf16 (RNE), single instruction
DEV unsigned cvtpk(float lo, float hi) {
  unsigned r;
  asm("v_cvt_pk_bf16_f32 %0, %1, %2" : "=v"(r) : "v"(lo), "v"(hi));
  return r;
}

// a' = {a.lo32, b.lo32}; b' = {a.hi32, b.hi32}
DEV void pl32swap(unsigned &a, unsigned &b) {
#if __has_builtin(__builtin_amdgcn_permlane32_swap)
  auto r = __builtin_amdgcn_permlane32_swap(a, b, false, false);
  a = r[0]; b = r[1];
#else
  asm("v_permlane32_swap_b32 %0, %1" : "+v"(a), "+v"(b));
#endif
}

// rows = 16-lane groups: a' = {a.r0, b.r0, a.r2, b.r2}; b' = {a.r1, b.r1, a.r3, b.r3}
DEV void pl16swap(unsigned &a, unsigned &b) {
#if __has_builtin(__builtin_amdgcn_permlane16_swap)
  auto r = __builtin_amdgcn_permlane16_swap(a, b, false, false);
  a = r[0]; b = r[1];
#else
  asm("v_permlane16_swap_b32 %0, %1" : "+v"(a), "+v"(b));
#endif
}

// symmetric fake-quant of a bf16x8 fragment in-register (deterministic:
// attn1 and attn2 produce IDENTICAL results from identical inputs).
DEV bf16x8 qfrag(uint4 w, float idq, float dq) {
  unsigned o[4];
  const unsigned* wi = &w.x;
  #pragma unroll
  for (int i = 0; i < 4; i++) {
    float lo = __uint_as_float(wi[i] << 16);
    float hi = __uint_as_float(wi[i] & 0xffff0000u);
    lo = fminf(fmaxf(rintf(lo * idq), -128.f), 127.f) * dq;
    hi = fminf(fmaxf(rintf(hi * idq), -128.f), 127.f) * dq;
    o[i] = cvtpk(lo, hi);
  }
  uint4 r = make_uint4(o[0], o[1], o[2], o[3]);
  return *(bf16x8*)&r;
}

// scal: [0..3]=wmax(q,kv,sr,proj), [4]=qmax, [5]=kmax, [6]=vmax, [7]=pmin, [8]=pmax
__global__ void k_init(float* scal) {
  int t = threadIdx.x;
  if (t < 16) scal[t] = (t == 7) ? __uint_as_float(0x7f800000u) : 0.f;
}

__global__ __launch_bounds__(256) void k_absmax4(const float* w0, const float* w1,
                                                 const float* w2, const float* w3, float* scal) {
  const float* srcs[4] = {w0, w1, w2, w3};
  const int ns[4] = {65536, 131072, 1048576, 65536};
  int t = blockIdx.y;
  const float* src = srcs[t];
  int n = ns[t];
  float m = 0.f;
  for (int i = blockIdx.x * 256 + threadIdx.x; i < n; i += gridDim.x * 256)
    m = fmaxf(m, fabsf(src[i]));
  #pragma unroll
  for (int d = 1; d < 64; d <<= 1) m = fmaxf(m, __shfl_xor(m, d, 64));
  __shared__ float red[4];
  if ((threadIdx.x & 63) == 0) red[threadIdx.x >> 6] = m;
  __syncthreads();
  if (threadIdx.x == 0) {
    m = fmaxf(fmaxf(red[0], red[1]), fmaxf(red[2], red[3]));
    atomicMax((unsigned*)(scal + t), __float_as_uint(m));
  }
}

// fused weight quant + x->bf16 cast, one dispatch (grid.x = 4096):
//   all blocks:  sr_w (1048576 elems) -> sr_wq with im2col-matched k-order
//                x (8388608 f32, 8/thread) -> xb bf16
//   bx < 512:    kv_w (131072)        -> kv_wq   (slot 1)
//   bx < 256:    q_w + proj_w (65536) -> q_wq / proj_wq (slots 0 / 3)
__global__ __launch_bounds__(256) void k_quantw(const float* qw, const float* kvw,
                                                const float* prw, const float* srw,
                                                const float* xf,
                                                unsigned short* qo, unsigned short* kvo,
                                                unsigned short* pro, unsigned short* sro,
                                                unsigned short* xbo,
                                                const float* scal) {
  int bx = blockIdx.x;
  int tid = bx * 256 + threadIdx.x;
  {
    int oo = tid >> 12;
    int rem = tid & 4095;
    int khkw = rem >> 8;
    int i = rem & 255;
    float delta = scal[2] / 127.f + 1e-8f;
    float x = srw[oo * 4096 + i * 16 + khkw];
    sro[tid] = f2bf(fminf(fmaxf(rintf(x / delta), -128.f), 127.f) * delta);
  }
  {
    // x cast: 8 contiguous f32 -> 8 bf16 per thread
    const float4* xs = (const float4*)(xf + (size_t)tid * 8);
    float4 v0 = xs[0], v1 = xs[1];
    unsigned w0 = ((unsigned)f2bf(v0.y) << 16) | f2bf(v0.x);
    unsigned w1 = ((unsigned)f2bf(v0.w) << 16) | f2bf(v0.z);
    unsigned w2 = ((unsigned)f2bf(v1.y) << 16) | f2bf(v1.x);
    unsigned w3 = ((unsigned)f2bf(v1.w) << 16) | f2bf(v1.z);
    *(uint4*)(xbo + (size_t)tid * 8) = make_uint4(w0, w1, w2, w3);
  }
  if (bx < 512) {
    float delta = scal[1] / 127.f + 1e-8f;
    kvo[tid] = f2bf(fminf(fmaxf(rintf(kvw[tid] / delta), -128.f), 127.f) * delta);
  }
  if (bx < 256) {
    float dq = scal[0] / 127.f + 1e-8f;
    qo[tid] = f2bf(fminf(fmaxf(rintf(qw[tid] / dq), -128.f), 127.f) * dq);
    float dp = scal[3] / 127.f + 1e-8f;
    pro[tid] = f2bf(fminf(fmaxf(rintf(prw[tid] / dp), -128.f), 127.f) * dp);
  }
}

// ---- 64x64-tile GEMM, K=256, BK=128 (kv: M=2048,N=512) ----
__global__ __launch_bounds__(256) void k_gemm_bk(const unsigned short* __restrict__ Ab,
                                                 const unsigned short* __restrict__ W,
                                                 const float* __restrict__ bias,
                                                 float* __restrict__ C,
                                                 int M, int N, float* max_ptr, int split) {
  __shared__ unsigned short As[64 * 136];
  __shared__ unsigned short Bs[64 * 136];
  const int m0 = blockIdx.y * 64, n0 = blockIdx.x * 64;
  const int tid = threadIdx.x;
  const int wid = tid >> 6, lane = tid & 63;
  const int quad = lane >> 4, lr = lane & 15;
  const int wm = wid >> 1, wn = wid & 1;
  f32x4 acc[2][2] = {};
  for (int kb = 0; kb < 256; kb += 128) {
    __syncthreads();
    #pragma unroll
    for (int i = 0; i < 4; i++) {
      int c = i * 256 + tid;              // 1024 chunks of 8 elems
      int row = c >> 4, cu = (c & 15) * 8;
      *(uint4*)&As[row * 136 + cu] = *(const uint4*)(Ab + (size_t)(m0 + row) * 256 + kb + cu);
      *(uint4*)&Bs[row * 136 + cu] = *(const uint4*)(W + (size_t)(n0 + row) * 256 + kb + cu);
    }
    __syncthreads();
    #pragma unroll
    for (int kc = 0; kc < 4; kc++) {
      bf16x8 af0 = *(const bf16x8*)&As[(wm * 32 + lr) * 136 + kc * 32 + quad * 8];
      bf16x8 af1 = *(const bf16x8*)&As[(wm * 32 + 16 + lr) * 136 + kc * 32 + quad * 8];
      bf16x8 bf0 = *(const bf16x8*)&Bs[(wn * 32 + lr) * 136 + kc * 32 + quad * 8];
      bf16x8 bf1 = *(const bf16x8*)&Bs[(wn * 32 + 16 + lr) * 136 + kc * 32 + quad * 8];
      acc[0][0] = __builtin_amdgcn_mfma_f32_16x16x32_bf16(af0, bf0, acc[0][0], 0, 0, 0);
      acc[0][1] = __builtin_amdgcn_mfma_f32_16x16x32_bf16(af0, bf1, acc[0][1], 0, 0, 0);
      acc[1][0] = __builtin_amdgcn_mfma_f32_16x16x32_bf16(af1, bf0, acc[1][0], 0, 0, 0);
      acc[1][1] = __builtin_amdgcn_mfma_f32_16x16x32_bf16(af1, bf1, acc[1][1], 0, 0, 0);
    }
  }
  float amax = 0.f;
  #pragma unroll
  for (int mi = 0; mi < 2; mi++)
    #pragma unroll
    for (int ni = 0; ni < 2; ni++) {
      int col = n0 + wn * 32 + ni * 16 + lr;
      float bv = bias[col];
      #pragma unroll
      for (int r = 0; r < 4; r++) {
        int row = m0 + wm * 32 + mi * 16 + quad * 4 + r;
        float v = acc[mi][ni][r] + bv;
        C[(size_t)row * N + col] = v;
        amax = fmaxf(amax, fabsf(v));
      }
    }
  if (max_ptr) {
    #pragma unroll
    for (int d = 1; d < 64; d <<= 1) amax = fmaxf(amax, __shfl_xor(amax, d, 64));
    if (lane == 0) {
      int slot = (split > 0 && n0 >= split) ? 1 : 0;
      atomicMax((unsigned*)(max_ptr + slot), __float_as_uint(amax));
    }
  }
}

// ---- 128x128-tile GEMM, M=32768 N=256 K=256, BK=64; bf16 A; flat grid 512
// XCD swizzle: the 2 n-blocks sharing an A-tile land on the SAME XCD, adjacent
// in dispatch order -> A re-read comes from that XCD's L2.
// MODE 0: f32 linear C (proj -> out). MODE 1: bf16 q written PERMUTED into
// qq[b,h,n,j] (UN-quantized; attn kernels quantize on load), amax still f32. ----
template<int MODE>
__global__ __launch_bounds__(256) void k_gemm128(const unsigned short* __restrict__ Ab,
                                                 const unsigned short* __restrict__ W,
                                                 const float* __restrict__ bias,
                                                 void* __restrict__ Cout,
                                                 float* max_ptr) {
  __shared__ unsigned short As[128 * 72];  // +8 pad: 2-way-max banking
  __shared__ unsigned short Bs[128 * 72];
  const int id = blockIdx.x;
  const int xcd = id & 7, idx = id >> 3;          // 64 blocks per XCD
  const int mt = xcd * 32 + (idx >> 1), nt = idx & 1;
  const int m0 = mt * 128, n0 = nt * 128;
  const int tid = threadIdx.x;
  const int wid = tid >> 6, lane = tid & 63;   // 4 waves
  const int quad = lane >> 4, lr = lane & 15;
  const int wm = wid >> 1, wn = wid & 1;       // 2x2 wave grid, 64x64 patch each
  f32x4 acc[4][4] = {};
  for (int kb = 0; kb < 256; kb += 64) {
    __syncthreads();
    #pragma unroll
    for (int i = 0; i < 4; i++) {
      int c = i * 256 + tid;             // 1024 chunks of 8 shorts
      int row = c >> 3, cu = (c & 7) * 8;
      *(uint4*)&As[row * 72 + cu] = *(const uint4*)(Ab + (size_t)(m0 + row) * 256 + kb + cu);
      *(uint4*)&Bs[row * 72 + cu] = *(const uint4*)(W + (size_t)(n0 + row) * 256 + kb + cu);
    }
    __syncthreads();
    #pragma unroll
    for (int kc = 0; kc < 2; kc++) {
      bf16x8 af[4], bf[4];
      #pragma unroll
      for (int mi = 0; mi < 4; mi++)
        af[mi] = *(const bf16x8*)&As[(wm * 64 + mi * 16 + lr) * 72 + kc * 32 + quad * 8];
      #pragma unroll
      for (int ni = 0; ni < 4; ni++)
        bf[ni] = *(const bf16x8*)&Bs[(wn * 64 + ni * 16 + lr) * 72 + kc * 32 + quad * 8];
      #pragma unroll
      for (int mi = 0; mi < 4; mi++)
        #pragma unroll
        for (int ni = 0; ni < 4; ni++)
          acc[mi][ni] = __builtin_amdgcn_mfma_f32_16x16x32_bf16(af[mi], bf[ni], acc[mi][ni], 0, 0, 0);
    }
  }
  float amax = 0.f;
  #pragma unroll
  for (int mi = 0; mi < 4; mi++)
    #pragma unroll
    for (int ni = 0; ni < 4; ni++) {
      int col = n0 + wn * 64 + ni * 16 + lr;
      float bv = bias[col];
      #pragma unroll
      for (int r = 0; r < 4; r++) {
        int row = m0 + wm * 64 + mi * 16 + quad * 4 + r;
        float v = acc[mi][ni][r] + bv;
        if (MODE == 0) {
          ((float*)Cout)[(size_t)row * 256 + col] = v;
        } else {
          int b = row >> 12, nn = row & 4095;
          int h = col >> 5, j = col & 31;
          ((unsigned short*)Cout)[((size_t)(b * 8 + h) * 4096 + nn) * 32 + j] = f2bf(v);
        }
        amax = fmaxf(amax, fabsf(v));
      }
    }
  if (max_ptr) {
    #pragma unroll
    for (int d = 1; d < 64; d <<= 1) amax = fmaxf(amax, __shfl_xor(amax, d, 64));
    if (lane == 0) atomicMax((unsigned*)max_ptr, __float_as_uint(amax));
  }
}

// ---- conv GEMM: 2048x256xK4096, split-K=4, im2col fused (bf16 x); flat grid 512
// XCD swizzle: per XCD a fixed k-split z and 16 m-tiles x 4 n-tiles; the 4
// n-blocks sharing an A-tile are same-XCD + dispatch-adjacent -> L2 A-reuse. ----
__global__ __launch_bounds__(256) void k_conv_sk(const unsigned short* __restrict__ xb,
                                                 const unsigned short* __restrict__ W,
                                                 float* __restrict__ C) {
  __shared__ unsigned short As[64 * 136];
  __shared__ unsigned short Bs[64 * 136];
  const int id = blockIdx.x;
  const int xcd = id & 7, idx = id >> 3;     // 64 blocks per XCD
  const int a = idx >> 2, nt = idx & 3;
  const int ag = xcd * 16 + a;               // 128 A-groups = (m-tile, z)
  const int mt = ag & 31, z = ag >> 5;
  const int m0 = mt * 64, n0 = nt * 64;
  const int kOff = z * 1024;
  C += (size_t)z * 2048 * 256;
  const int tid = threadIdx.x;
  const int wid = tid >> 6, lane = tid & 63;
  const int quad = lane >> 4, lr = lane & 15;
  const int wm = wid >> 1, wn = wid & 1;
  f32x4 acc[2][2] = {};
  for (int kb = 0; kb < 1024; kb += 128) {
    __syncthreads();
    #pragma unroll
    for (int i = 0; i < 4; i++) {
      int c = i * 256 + tid;
      int row = c >> 4, cu = (c & 15) * 8;
      int kk = kOff + kb + cu;
      int m = m0 + row;
      int b = m >> 8, p = m & 255, ph = p >> 4, pw = p & 15;
      int q = kk >> 8, ii = kk & 255;
      int n = (ph * 4 + (q >> 2)) * 64 + pw * 4 + (q & 3);
      *(uint4*)&As[row * 136 + cu] = *(const uint4*)(xb + ((size_t)(b * 4096 + n) * 256 + ii));
      *(uint4*)&Bs[row * 136 + cu] = *(const uint4*)(W + (size_t)(n0 + row) * 4096 + kk);
    }
    __syncthreads();
    #pragma unroll
    for (int kc = 0; kc < 4; kc++) {
      bf16x8 af0 = *(const bf16x8*)&As[(wm * 32 + lr) * 136 + kc * 32 + quad * 8];
      bf16x8 af1 = *(const bf16x8*)&As[(wm * 32 + 16 + lr) * 136 + kc * 32 + quad * 8];
      bf16x8 bf0 = *(const bf16x8*)&Bs[(wn * 32 + lr) * 136 + kc * 32 + quad * 8];
      bf16x8 bf1 = *(const bf16x8*)&Bs[(wn * 32 + 16 + lr) * 136 + kc * 32 + quad * 8];
      acc[0][0] = __builtin_amdgcn_mfma_f32_16x16x32_bf16(af0, bf0, acc[0][0], 0, 0, 0);
      acc[0][1] = __builtin_amdgcn_mfma_f32_16x16x32_bf16(af0, bf1, acc[0][1], 0, 0, 0);
      acc[1][0] = __builtin_amdgcn_mfma_f32_16x16x32_bf16(af1, bf0, acc[1][0], 0, 0, 0);
      acc[1][1] = __builtin_amdgcn_mfma_f32_16x16x32_bf16(af1, bf1, acc[1][1], 0, 0, 0);
    }
  }
  #pragma unroll
  for (int mi = 0; mi < 2; mi++)
    #pragma unroll
    for (int ni = 0; ni < 2; ni++) {
      int col = n0 + wn * 32 + ni * 16 + lr;
      #pragma unroll
      for (int r = 0; r < 4; r++) {
        int row = m0 + wm * 32 + mi * 16 + quad * 4 + r;
        C[(size_t)row * 256 + col] = acc[mi][ni][r];
      }
    }
}

// LayerNorm over C=256; sums 4 split-K conv partials + sr_b first
__global__ __launch_bounds__(256) void k_ln(const float* __restrict__ convp, const float* srb,
                                            const float* g, const float* bb,
                                            unsigned short* __restrict__ xn) {
  int row = blockIdx.x, c = threadIdx.x;
  float v = srb[c];
  #pragma unroll
  for (int s = 0; s < 4; s++) v += convp[s * 524288 + row * 256 + c];
  __shared__ float red[4];
  float s = v;
  #pragma unroll
  for (int d = 1; d < 64; d <<= 1) s += __shfl_xor(s, d, 64);
  if ((c & 63) == 0) red[c >> 6] = s;
  __syncthreads();
  float mu = (red[0] + red[1] + red[2] + red[3]) * (1.f / 256.f);
  __syncthreads();
  float dv = v - mu;
  float s2 = dv * dv;
  #pragma unroll
  for (int d = 1; d < 64; d <<= 1) s2 += __shfl_xor(s2, d, 64);
  if ((c & 63) == 0) red[c >> 6] = s2;
  __syncthreads();
  float var = (red[0] + red[1] + red[2] + red[3]) * (1.f / 256.f);
  float rs = 1.f / sqrtf(var + 1e-5f);
  xn[row * 256 + c] = f2bf(dv * rs * g[c] + bb[c]);
}

// kv activation quant (grid.x = 1024): kv (2048x512 f32) ->
// kq[b,h,n2,j] / vqt[b,h,j,n2] bf16, 4 elems/thread
__global__ __launch_bounds__(256) void k_quant_kv(const float* __restrict__ kv,
                                                  unsigned short* __restrict__ kq,
                                                  unsigned short* __restrict__ vqt,
                                                  const float* scal) {
  int tid4 = blockIdx.x * 256 + threadIdx.x;
  int i4 = tid4 * 4;
  int row = i4 >> 9, d0 = i4 & 511;
  int b = row >> 8, n2 = row & 255;
  int t = d0 >> 8, hj = d0 & 255;
  int h = hj >> 5, j = hj & 31;   // j multiple of 4, j+3 <= 31 (same t,h for all 4)
  float delta = scal[5 + t] / 127.f + 1e-8f;
  float4 v = *(const float4*)(kv + i4);
  unsigned short r0 = f2bf(fminf(fmaxf(rintf(v.x / delta), -128.f), 127.f) * delta);
  unsigned short r1 = f2bf(fminf(fmaxf(rintf(v.y / delta), -128.f), 127.f) * delta);
  unsigned short r2 = f2bf(fminf(fmaxf(rintf(v.z / delta), -128.f), 127.f) * delta);
  unsigned short r3 = f2bf(fminf(fmaxf(rintf(v.w / delta), -128.f), 127.f) * delta);
  if (t == 0) {
    ushort4 rr = make_ushort4(r0, r1, r2, r3);
    *(ushort4*)(kq + ((size_t)((b * 8 + h) * 256 + n2) * 32) + j) = rr;
  } else {
    size_t base = (size_t)(b * 8 + h) * 32 * 256 + n2;
    vqt[base + (size_t)(j + 0) * 256] = r0;
    vqt[base + (size_t)(j + 1) * 256] = r1;
    vqt[base + (size_t)(j + 2) * 256] = r2;
    vqt[base + (size_t)(j + 3) * 256] = r3;
  }
}

// attention pass 1 (R14): swapped QK^T, K staged lane-major in LDS; q fragment
// quantized IN-REGISTER on load (qq holds unquantized bf16 q from the GEMM);
// per-block (wmin,wmax) folded into scal[7]/[8] via uint atomics (floats >= 0).
__global__ __launch_bounds__(256) void k_attn1(const unsigned short* __restrict__ qq,
                                               const unsigned short* __restrict__ kq,
                                               float2* __restrict__ rowstats,
                                               float* scal) {
  __shared__ unsigned short KsL[8192];  // 16 KB: [t(16)][lane(64)] x 8 shorts
  __shared__ float red[8];
  const int bh = blockIdx.y;
  const int row0 = blockIdx.x * 256;
  const int tid = threadIdx.x, wid = tid >> 6, lane = tid & 63, quad = lane >> 4, lr = lane & 15;
  const float c2 = 0.17677669529663687f * 1.4426950408889634f;  // 32^-0.5 * log2(e)
  const unsigned short* kb = kq + (size_t)bh * 8192;
  #pragma unroll
  for (int k = 0; k < 4; k++) {
    int cid = k * 256 + tid;                 // 1024 chunks of 16B
    int seg = cid >> 6, lc = cid & 63, qc = lc >> 4, lrc = lc & 15;
    *(uint4*)&KsL[cid * 8] = *(const uint4*)(kb + (seg * 16 + lrc) * 32 + qc * 8);
  }
  float dq = scal[4] / 127.f + 1e-8f;
  float idq = 1.f / dq;
  __syncthreads();
  float wmin = 1e30f, wmax = 0.f;
  #pragma unroll
  for (int g = 0; g < 4; g++) {
    int rowg = row0 + g * 64 + wid * 16 + lr;
    uint4 qw = *(const uint4*)(qq + ((size_t)bh * 4096 + rowg) * 32 + quad * 8);
    bf16x8 qf = qfrag(qw, idq, dq);
    f32x4 acc[16] = {};
    // acc[t][r] = S_raw[key = 16t + 4*quad + r][qrow = rowg]
    #pragma unroll
    for (int t = 0; t < 16; t++) {
      bf16x8 kf = *(const bf16x8*)&KsL[(t * 64 + quad * 16 + lr) * 8];
      acc[t] = __builtin_amdgcn_mfma_f32_16x16x32_bf16(kf, qf, acc[t], 0, 0, 0);
    }
    float mxr = -1e30f, mnr = 1e30f;
    #pragma unroll
    for (int t = 0; t < 16; t++)
      #pragma unroll
      for (int r = 0; r < 4; r++) {
        float s = acc[t][r];
        mxr = fmaxf(mxr, s); mnr = fminf(mnr, s);
      }
    #pragma unroll
    for (int d = 16; d < 64; d <<= 1) {
      mxr = fmaxf(mxr, __shfl_xor(mxr, d, 64));
      mnr = fminf(mnr, __shfl_xor(mnr, d, 64));
    }
    float m2 = mxr * c2;
    float l = 0.f;
    #pragma unroll
    for (int t = 0; t < 16; t++)
      #pragma unroll
      for (int r = 0; r < 4; r++)
        l += exp2_(fmaf(acc[t][r], c2, -m2));
    #pragma unroll
    for (int d = 16; d < 64; d <<= 1) l += __shfl_xor(l, d, 64);
    float inv_l = 1.f / l;
    if (lane < 16)   // quad 0: 16 coalesced float2 writes per wave
      rowstats[(size_t)bh * 4096 + rowg] = make_float2(m2, inv_l);
    wmax = fmaxf(wmax, inv_l);
    wmin = fminf(wmin, exp2_((mnr - mxr) * c2) * inv_l);
  }
  #pragma unroll
  for (int d = 1; d < 16; d <<= 1) {
    wmax = fmaxf(wmax, __shfl_xor(wmax, d, 64));
    wmin = fminf(wmin, __shfl_xor(wmin, d, 64));
  }
  if (lane == 0) { red[wid] = wmin; red[4 + wid] = wmax; }
  __syncthreads();
  if (tid == 0) {
    float mn = fminf(fminf(red[0], red[1]), fminf(red[2], red[3]));
    float mx = fmaxf(fmaxf(red[4], red[5]), fmaxf(red[6], red[7]));
    // pmin/pmax are positive floats: uint compare == float compare
    atomicMin((unsigned*)(scal + 7), __float_as_uint(mn));
    atomicMax((unsigned*)(scal + 8), __float_as_uint(mx));
  }
}

// attention pass 2 (R14): swapped-QK in-register softmax/quant; K/V staged
// lane-major in LDS (zero-conflict); q fragment quantized in-register on load
// (identical function of identical inputs as attn1 => consistent).
__global__ __launch_bounds__(256) void k_attn2(const unsigned short* __restrict__ qq,
                                               const unsigned short* __restrict__ kq,
                                               const unsigned short* __restrict__ vqt,
                                               const float* scal,
                                               const float2* __restrict__ rowstats,
                                               unsigned short* __restrict__ attn_out) {
  __shared__ unsigned short KsL[8192];  // 16 KB: [t(16)][lane(64)] chunks
  __shared__ unsigned short VsL[8192];  // 16 KB: [ks*2+half(16)][lane(64)] chunks
  const int bh = blockIdx.y, b = bh >> 3, h = bh & 7;
  const int row0 = blockIdx.x * 256;
  const int tid = threadIdx.x, wid = tid >> 6, lane = tid & 63, quad = lane >> 4, lr = lane & 15;
  const float c2 = 0.17677669529663687f * 1.4426950408889634f;
  const unsigned short* kb = kq + (size_t)bh * 8192;
  const unsigned short* vb = vqt + (size_t)bh * 8192;
  #pragma unroll
  for (int k = 0; k < 4; k++) {
    int cid = k * 256 + tid;
    int seg = cid >> 6, lc = cid & 63, qc = lc >> 4, lrc = lc & 15;
    // K chunk (t=seg): kq row seg*16+lrc, dh slice qc*8
    *(uint4*)&KsL[cid * 8] = *(const uint4*)(kb + (seg * 16 + lrc) * 32 + qc * 8);
    // V chunk (ks=seg>>1, half=seg&1): vqt row half*16+lrc, key slice ks*32+qc*8
    *(uint4*)&VsL[cid * 8] =
        *(const uint4*)(vb + ((seg & 1) * 16 + lrc) * 256 + (seg >> 1) * 32 + qc * 8);
  }
  float dq = scal[4] / 127.f + 1e-8f;
  float idq = 1.f / dq;
  float pmin = scal[7], pmax = scal[8];
  float delta = (pmax - pmin) / 255.f + 1e-8f;
  float zp = rintf(-pmin / delta);
  float qlo = -zp, qhi = 255.f - zp;
  __syncthreads();
  #pragma unroll
  for (int g = 0; g < 4; g++) {
    int rowg = row0 + g * 64 + wid * 16 + lr;
    uint4 qw = *(const uint4*)(qq + ((size_t)bh * 4096 + rowg) * 32 + quad * 8);
    bf16x8 qf = qfrag(qw, idq, dq);
    float2 st = rowstats[(size_t)bh * 4096 + rowg];
    f32x4 acc[16] = {};
    // acc[t][r] = S[key = 16t + 4*quad + r][qrow = rowg]
    #pragma unroll
    for (int t = 0; t < 16; t++) {
      bf16x8 kf = *(const bf16x8*)&KsL[(t * 64 + quad * 16 + lr) * 8];
      acc[t] = __builtin_amdgcn_mfma_f32_16x16x32_bf16(kf, qf, acc[t], 0, 0, 0);
    }
    // p*inv_delta = exp2(s*c2 - m2 + log2(inv_l/delta)); out = clamp(rint(.),qlo,qhi)*delta
    float ofs = __log2f(st.y / delta) - st.x;
    f32x4 o0 = {}, o1 = {};
    #pragma unroll
    for (int ks = 0; ks < 8; ks++) {
      float pv[8];
      #pragma unroll
      for (int half = 0; half < 2; half++) {
        #pragma unroll
        for (int r = 0; r < 4; r++) {
          float v = exp2_(fmaf(acc[2 * ks + half][r], c2, ofs));
          pv[half * 4 + r] = fminf(fmaxf(rintf(v), qlo), qhi) * delta;
        }
      }
      // pack to bf16 pairs and redistribute across quads into the MFMA A-fragment
      unsigned wa = cvtpk(pv[0], pv[1]);
      unsigned wb = cvtpk(pv[2], pv[3]);
      unsigned wc = cvtpk(pv[4], pv[5]);
      unsigned wd = cvtpk(pv[6], pv[7]);
      pl32swap(wa, wc);
      pl16swap(wa, wc);   // wa=F0, wc=F2
      pl32swap(wb, wd);
      pl16swap(wb, wd);   // wb=F1, wd=F3
      uint4 w = make_uint4(wa, wb, wc, wd);
      bf16x8 pa = *(bf16x8*)&w;
      bf16x8 b0 = *(const bf16x8*)&VsL[((ks * 2 + 0) * 64 + quad * 16 + lr) * 8];
      bf16x8 b1 = *(const bf16x8*)&VsL[((ks * 2 + 1) * 64 + quad * 16 + lr) * 8];
      o0 = __builtin_amdgcn_mfma_f32_16x16x32_bf16(pa, b0, o0, 0, 0, 0);
      o1 = __builtin_amdgcn_mfma_f32_16x16x32_bf16(pa, b1, o1, 0, 0, 0);
    }
    #pragma unroll
    for (int r = 0; r < 4; r++) {
      int n = row0 + g * 64 + wid * 16 + quad * 4 + r;
      size_t base = ((size_t)(b * 4096) + n) * 256 + h * 32;
      attn_out[base + lr] = f2bf(o0[r]);
      attn_out[base + 16 + lr] = f2bf(o1[r]);
    }
  }
}

extern "C" void kernel_launch(void* const* d_in, const int* in_sizes, int n_in,
                              void* d_out, int out_size, void* d_ws, size_t ws_size,
                              hipStream_t stream) {
  const float* x      = (const float*)d_in[0];
  const float* q_w    = (const float*)d_in[1];
  const float* q_b    = (const float*)d_in[2];
  const float* kv_w   = (const float*)d_in[3];
  const float* kv_b   = (const float*)d_in[4];
  const float* sr_w   = (const float*)d_in[5];
  const float* sr_b   = (const float*)d_in[6];
  const float* norm_g = (const float*)d_in[7];
  const float* norm_b = (const float*)d_in[8];
  const float* proj_w = (const float*)d_in[9];
  const float* proj_b = (const float*)d_in[10];
  float* out = (float*)d_out;

  char* ws = (char*)d_ws;
  float* scal = (float*)ws;
  unsigned short* q_wq    = (unsigned short*)(ws + 256);       // 128 KB
  unsigned short* kv_wq   = (unsigned short*)(ws + 131328);    // 256 KB
  unsigned short* proj_wq = (unsigned short*)(ws + 393472);    // 128 KB
  unsigned short* sr_wq   = (unsigned short*)(ws + 524544);    // 2 MB   -> 2621696
  unsigned short* xn      = (unsigned short*)(ws + 2621696);   // 1 MB   -> 3670272
  float*          kv_f    = (float*)(ws + 3670272);            // 4 MB   -> 7864576
  unsigned short* kq      = (unsigned short*)(ws + 7864576);   // 1 MB   -> 8913152
  unsigned short* vqt     = (unsigned short*)(ws + 8913152);   // 1 MB   -> 9961728
  float2*         rowstats= (float2*)(ws + 9961728);           // 2 MB   -> 12058880
  float*          convp   = (float*)(ws + 12058880);           // 8 MB (4 partials) -> 20447488
  unsigned short* attn_o  = (unsigned short*)(ws + 12058880);  // over convp (dead after k_ln); 16 MB
  unsigned short* qq      = (unsigned short*)(ws + 45613312);  // 16 MB -> 62390528 (bf16 q, UNquantized)
  unsigned short* xb      = (unsigned short*)(ws + 62390528);  // 16 MB -> 79167744 (x as bf16)

  k_init<<<1, 64, 0, stream>>>(scal);
  k_absmax4<<<dim3(64, 4), 256, 0, stream>>>(q_w, kv_w, sr_w, proj_w, scal);
  // weight quant + x->bf16 cast
  k_quantw<<<4096, 256, 0, stream>>>(q_w, kv_w, proj_w, sr_w, x,
                                     q_wq, kv_wq, proj_wq, sr_wq, xb, scal);
  // conv GEMM (im2col fused, split-K=4, XCD-swizzled): 2048x256x4096
  k_conv_sk<<<512, 256, 0, stream>>>(xb, sr_wq, convp);
  k_ln<<<2048, 256, 0, stream>>>(convp, sr_b, norm_g, norm_b, xn);
  // kv GEMM: 2048x512x256
  k_gemm_bk<<<dim3(8, 32), 256, 0, stream>>>(xn, kv_wq, kv_b, kv_f, 2048, 512, scal + 5, 256);
  // q GEMM: 32768x256x256, 128-tile, XCD-swizzled; writes bf16 q permuted into qq
  k_gemm128<1><<<512, 256, 0, stream>>>(xb, q_wq, q_b, qq, scal + 4);
  // kv activation quant
  k_quant_kv<<<1024, 256, 0, stream>>>(kv_f, kq, vqt, scal);
  k_attn1<<<dim3(16, 64), 256, 0, stream>>>(qq, kq, rowstats, scal);
  k_attn2<<<dim3(16, 64), 256, 0, stream>>>(qq, kq, vqt, scal, rowstats, attn_o);
  // proj GEMM: 32768x256x256, 128-tile, XCD-swizzled
  k_gemm128<0><<<512, 256, 0, stream>>>(attn_o, proj_wq, proj_b, out, nullptr);
}

// Round 7
// 272.289 us; speedup vs baseline: 1.0183x; 1.0183x over previous
//
#include <hip/hip_runtime.h>
#include <stdint.h>

typedef float f32x4 __attribute__((ext_vector_type(4)));
typedef __bf16 bf16x8 __attribute__((ext_vector_type(8)));

#define DEV __device__ __forceinline__

DEV unsigned short f2bf(float f) {
  unsigned u = __float_as_uint(f);
  u += 0x7FFFu + ((u >> 16) & 1u);   // round-to-nearest-even
  return (unsigned short)(u >> 16);
}

DEV float exp2_(float x) {
#if __has_builtin(__builtin_amdgcn_exp2f)
  return __builtin_amdgcn_exp2f(x);   // raw v_exp_f32; args in [-60,0] => normal range
#else
  return exp2f(x);
#endif
}

// pack two f32 -> one u32 of 2 bf16 (RNE), single instruction
DEV unsigned cvtpk(float lo, float hi) {
  unsigned r;
  asm("v_cvt_pk_bf16_f32 %0, %1, %2" : "=v"(r) : "v"(lo), "v"(hi));
  return r;
}

// a' = {a.lo32, b.lo32}; b' = {a.hi32, b.hi32}
DEV void pl32swap(unsigned &a, unsigned &b) {
#if __has_builtin(__builtin_amdgcn_permlane32_swap)
  auto r = __builtin_amdgcn_permlane32_swap(a, b, false, false);
  a = r[0]; b = r[1];
#else
  asm("v_permlane32_swap_b32 %0, %1" : "+v"(a), "+v"(b));
#endif
}

// rows = 16-lane groups: a' = {a.r0, b.r0, a.r2, b.r2}; b' = {a.r1, b.r1, a.r3, b.r3}
DEV void pl16swap(unsigned &a, unsigned &b) {
#if __has_builtin(__builtin_amdgcn_permlane16_swap)
  auto r = __builtin_amdgcn_permlane16_swap(a, b, false, false);
  a = r[0]; b = r[1];
#else
  asm("v_permlane16_swap_b32 %0, %1" : "+v"(a), "+v"(b));
#endif
}

// symmetric fake-quant of 8 packed bf16 in-register (deterministic: every
// consumer of the same bytes + same delta produces IDENTICAL results).
DEV uint4 qfrag4(uint4 w, float idq, float dq) {
  unsigned o[4];
  const unsigned* wi = &w.x;
  #pragma unroll
  for (int i = 0; i < 4; i++) {
    float lo = __uint_as_float(wi[i] << 16);
    float hi = __uint_as_float(wi[i] & 0xffff0000u);
    lo = fminf(fmaxf(rintf(lo * idq), -128.f), 127.f) * dq;
    hi = fminf(fmaxf(rintf(hi * idq), -128.f), 127.f) * dq;
    o[i] = cvtpk(lo, hi);
  }
  return make_uint4(o[0], o[1], o[2], o[3]);
}

DEV bf16x8 qfrag(uint4 w, float idq, float dq) {
  uint4 r = qfrag4(w, idq, dq);
  return *(bf16x8*)&r;
}

// scal: [0..3]=wmax(q,kv,sr,proj), [4]=qmax, [5]=kmax, [6]=vmax, [7]=pmin, [8]=pmax
__global__ void k_init(float* scal) {
  int t = threadIdx.x;
  if (t < 16) scal[t] = (t == 7) ? __uint_as_float(0x7f800000u) : 0.f;
}

__global__ __launch_bounds__(256) void k_absmax4(const float* w0, const float* w1,
                                                 const float* w2, const float* w3, float* scal) {
  const float* srcs[4] = {w0, w1, w2, w3};
  const int ns[4] = {65536, 131072, 1048576, 65536};
  int t = blockIdx.y;
  const float* src = srcs[t];
  int n = ns[t];
  float m = 0.f;
  for (int i = blockIdx.x * 256 + threadIdx.x; i < n; i += gridDim.x * 256)
    m = fmaxf(m, fabsf(src[i]));
  #pragma unroll
  for (int d = 1; d < 64; d <<= 1) m = fmaxf(m, __shfl_xor(m, d, 64));
  __shared__ float red[4];
  if ((threadIdx.x & 63) == 0) red[threadIdx.x >> 6] = m;
  __syncthreads();
  if (threadIdx.x == 0) {
    m = fmaxf(fmaxf(red[0], red[1]), fmaxf(red[2], red[3]));
    atomicMax((unsigned*)(scal + t), __float_as_uint(m));
  }
}

// fused weight quant + x->bf16 cast, one dispatch (grid.x = 4096):
//   all blocks:  sr_w (1048576 elems) -> sr_wq with im2col-matched k-order
//                x (8388608 f32, 8/thread) -> xb bf16
//   bx < 512:    kv_w (131072)        -> kv_wq   (slot 1)
//   bx < 256:    q_w + proj_w (65536) -> q_wq / proj_wq (slots 0 / 3)
__global__ __launch_bounds__(256) void k_quantw(const float* qw, const float* kvw,
                                                const float* prw, const float* srw,
                                                const float* xf,
                                                unsigned short* qo, unsigned short* kvo,
                                                unsigned short* pro, unsigned short* sro,
                                                unsigned short* xbo,
                                                const float* scal) {
  int bx = blockIdx.x;
  int tid = bx * 256 + threadIdx.x;
  {
    int oo = tid >> 12;
    int rem = tid & 4095;
    int khkw = rem >> 8;
    int i = rem & 255;
    float delta = scal[2] / 127.f + 1e-8f;
    float x = srw[oo * 4096 + i * 16 + khkw];
    sro[tid] = f2bf(fminf(fmaxf(rintf(x / delta), -128.f), 127.f) * delta);
  }
  {
    // x cast: 8 contiguous f32 -> 8 bf16 per thread
    const float4* xs = (const float4*)(xf + (size_t)tid * 8);
    float4 v0 = xs[0], v1 = xs[1];
    unsigned w0 = ((unsigned)f2bf(v0.y) << 16) | f2bf(v0.x);
    unsigned w1 = ((unsigned)f2bf(v0.w) << 16) | f2bf(v0.z);
    unsigned w2 = ((unsigned)f2bf(v1.y) << 16) | f2bf(v1.x);
    unsigned w3 = ((unsigned)f2bf(v1.w) << 16) | f2bf(v1.z);
    *(uint4*)(xbo + (size_t)tid * 8) = make_uint4(w0, w1, w2, w3);
  }
  if (bx < 512) {
    float delta = scal[1] / 127.f + 1e-8f;
    kvo[tid] = f2bf(fminf(fmaxf(rintf(kvw[tid] / delta), -128.f), 127.f) * delta);
  }
  if (bx < 256) {
    float dq = scal[0] / 127.f + 1e-8f;
    qo[tid] = f2bf(fminf(fmaxf(rintf(qw[tid] / dq), -128.f), 127.f) * dq);
    float dp = scal[3] / 127.f + 1e-8f;
    pro[tid] = f2bf(fminf(fmaxf(rintf(prw[tid] / dp), -128.f), 127.f) * dp);
  }
}

// ---- FUSED kv-GEMM + q-GEMM, one dispatch (768 blocks) ----
// blocks [0,256):   kv GEMM 2048x512x256, 64x64 tile, BK=128; writes k and v
//                   UNQUANTIZED bf16 directly in permuted layouts
//                   (kqu[b,h,n2,j], vqtu[b,h,j,n2]); amax -> scal[5]/[6].
// blocks [256,768): q GEMM 32768x256x256, 128x128 tile, XCD-swizzled; writes
//                   UNQUANTIZED bf16 q permuted into qq[b,h,n,j]; amax -> scal[4].
// Consumers (attn1/attn2) fake-quant deterministically on load.
__global__ __launch_bounds__(256) void k_gemm_qkv(const unsigned short* __restrict__ xnrm,
                                                  const unsigned short* __restrict__ kvw,
                                                  const float* __restrict__ kvb,
                                                  const unsigned short* __restrict__ xb,
                                                  const unsigned short* __restrict__ qw,
                                                  const float* __restrict__ qb,
                                                  unsigned short* __restrict__ kqu,
                                                  unsigned short* __restrict__ vqtu,
                                                  unsigned short* __restrict__ qq,
                                                  float* scal) {
  __shared__ unsigned short smem[18432];  // 36.9 KB union
  const int tid = threadIdx.x;
  const int wid = tid >> 6, lane = tid & 63;
  const int quad = lane >> 4, lr = lane & 15;
  const int wm = wid >> 1, wn = wid & 1;
  if (blockIdx.x < 256) {
    // ---------------- kv GEMM ----------------
    unsigned short* As = smem;            // 64*136
    unsigned short* Bs = smem + 8704;     // 64*136
    const int n0 = (blockIdx.x & 7) * 64, m0 = (blockIdx.x >> 3) * 64;
    f32x4 acc[2][2] = {};
    for (int kb = 0; kb < 256; kb += 128) {
      __syncthreads();
      #pragma unroll
      for (int i = 0; i < 4; i++) {
        int c = i * 256 + tid;
        int row = c >> 4, cu = (c & 15) * 8;
        *(uint4*)&As[row * 136 + cu] = *(const uint4*)(xnrm + (size_t)(m0 + row) * 256 + kb + cu);
        *(uint4*)&Bs[row * 136 + cu] = *(const uint4*)(kvw + (size_t)(n0 + row) * 256 + kb + cu);
      }
      __syncthreads();
      #pragma unroll
      for (int kc = 0; kc < 4; kc++) {
        bf16x8 af0 = *(const bf16x8*)&As[(wm * 32 + lr) * 136 + kc * 32 + quad * 8];
        bf16x8 af1 = *(const bf16x8*)&As[(wm * 32 + 16 + lr) * 136 + kc * 32 + quad * 8];
        bf16x8 bf0 = *(const bf16x8*)&Bs[(wn * 32 + lr) * 136 + kc * 32 + quad * 8];
        bf16x8 bf1 = *(const bf16x8*)&Bs[(wn * 32 + 16 + lr) * 136 + kc * 32 + quad * 8];
        acc[0][0] = __builtin_amdgcn_mfma_f32_16x16x32_bf16(af0, bf0, acc[0][0], 0, 0, 0);
        acc[0][1] = __builtin_amdgcn_mfma_f32_16x16x32_bf16(af0, bf1, acc[0][1], 0, 0, 0);
        acc[1][0] = __builtin_amdgcn_mfma_f32_16x16x32_bf16(af1, bf0, acc[1][0], 0, 0, 0);
        acc[1][1] = __builtin_amdgcn_mfma_f32_16x16x32_bf16(af1, bf1, acc[1][1], 0, 0, 0);
      }
    }
    float amax = 0.f;
    #pragma unroll
    for (int mi = 0; mi < 2; mi++)
      #pragma unroll
      for (int ni = 0; ni < 2; ni++) {
        int col = n0 + wn * 32 + ni * 16 + lr;
        float bv = kvb[col];
        #pragma unroll
        for (int r = 0; r < 4; r++) {
          int row = m0 + wm * 32 + mi * 16 + quad * 4 + r;
          float v = acc[mi][ni][r] + bv;
          int b = row >> 8, n2 = row & 255;
          int h = (col >> 5) & 7, j = col & 31;
          if (col < 256)
            kqu[((size_t)((b * 8 + h) * 256 + n2)) * 32 + j] = f2bf(v);
          else
            vqtu[((size_t)((b * 8 + h) * 32 + j)) * 256 + n2] = f2bf(v);
          amax = fmaxf(amax, fabsf(v));
        }
      }
    #pragma unroll
    for (int d = 1; d < 64; d <<= 1) amax = fmaxf(amax, __shfl_xor(amax, d, 64));
    if (lane == 0)
      atomicMax((unsigned*)(scal + 5 + (n0 >= 256 ? 1 : 0)), __float_as_uint(amax));
  } else {
    // ---------------- q GEMM (XCD-swizzled 128x128) ----------------
    unsigned short* As = smem;            // 128*72
    unsigned short* Bs = smem + 9216;     // 128*72
    const int id = blockIdx.x - 256;
    const int xcd = id & 7, idx = id >> 3;          // 64 blocks per XCD
    const int mt = xcd * 32 + (idx >> 1), nt = idx & 1;
    const int m0 = mt * 128, n0 = nt * 128;
    f32x4 acc[4][4] = {};
    for (int kb = 0; kb < 256; kb += 64) {
      __syncthreads();
      #pragma unroll
      for (int i = 0; i < 4; i++) {
        int c = i * 256 + tid;
        int row = c >> 3, cu = (c & 7) * 8;
        *(uint4*)&As[row * 72 + cu] = *(const uint4*)(xb + (size_t)(m0 + row) * 256 + kb + cu);
        *(uint4*)&Bs[row * 72 + cu] = *(const uint4*)(qw + (size_t)(n0 + row) * 256 + kb + cu);
      }
      __syncthreads();
      #pragma unroll
      for (int kc = 0; kc < 2; kc++) {
        bf16x8 af[4], bf[4];
        #pragma unroll
        for (int mi = 0; mi < 4; mi++)
          af[mi] = *(const bf16x8*)&As[(wm * 64 + mi * 16 + lr) * 72 + kc * 32 + quad * 8];
        #pragma unroll
        for (int ni = 0; ni < 4; ni++)
          bf[ni] = *(const bf16x8*)&Bs[(wn * 64 + ni * 16 + lr) * 72 + kc * 32 + quad * 8];
        #pragma unroll
        for (int mi = 0; mi < 4; mi++)
          #pragma unroll
          for (int ni = 0; ni < 4; ni++)
            acc[mi][ni] = __builtin_amdgcn_mfma_f32_16x16x32_bf16(af[mi], bf[ni], acc[mi][ni], 0, 0, 0);
      }
    }
    float amax = 0.f;
    #pragma unroll
    for (int mi = 0; mi < 4; mi++)
      #pragma unroll
      for (int ni = 0; ni < 4; ni++) {
        int col = n0 + wn * 64 + ni * 16 + lr;
        float bv = qb[col];
        #pragma unroll
        for (int r = 0; r < 4; r++) {
          int row = m0 + wm * 64 + mi * 16 + quad * 4 + r;
          float v = acc[mi][ni][r] + bv;
          int b = row >> 12, nn = row & 4095;
          int h = col >> 5, j = col & 31;
          qq[((size_t)(b * 8 + h) * 4096 + nn) * 32 + j] = f2bf(v);
          amax = fmaxf(amax, fabsf(v));
        }
      }
    #pragma unroll
    for (int d = 1; d < 64; d <<= 1) amax = fmaxf(amax, __shfl_xor(amax, d, 64));
    if (lane == 0) atomicMax((unsigned*)(scal + 4), __float_as_uint(amax));
  }
}

// ---- 128x128-tile GEMM (proj): f32 C out, XCD-swizzled ----
__global__ __launch_bounds__(256) void k_gemm128(const unsigned short* __restrict__ Ab,
                                                 const unsigned short* __restrict__ W,
                                                 const float* __restrict__ bias,
                                                 float* __restrict__ C) {
  __shared__ unsigned short As[128 * 72];
  __shared__ unsigned short Bs[128 * 72];
  const int id = blockIdx.x;
  const int xcd = id & 7, idx = id >> 3;
  const int mt = xcd * 32 + (idx >> 1), nt = idx & 1;
  const int m0 = mt * 128, n0 = nt * 128;
  const int tid = threadIdx.x;
  const int wid = tid >> 6, lane = tid & 63;
  const int quad = lane >> 4, lr = lane & 15;
  const int wm = wid >> 1, wn = wid & 1;
  f32x4 acc[4][4] = {};
  for (int kb = 0; kb < 256; kb += 64) {
    __syncthreads();
    #pragma unroll
    for (int i = 0; i < 4; i++) {
      int c = i * 256 + tid;
      int row = c >> 3, cu = (c & 7) * 8;
      *(uint4*)&As[row * 72 + cu] = *(const uint4*)(Ab + (size_t)(m0 + row) * 256 + kb + cu);
      *(uint4*)&Bs[row * 72 + cu] = *(const uint4*)(W + (size_t)(n0 + row) * 256 + kb + cu);
    }
    __syncthreads();
    #pragma unroll
    for (int kc = 0; kc < 2; kc++) {
      bf16x8 af[4], bf[4];
      #pragma unroll
      for (int mi = 0; mi < 4; mi++)
        af[mi] = *(const bf16x8*)&As[(wm * 64 + mi * 16 + lr) * 72 + kc * 32 + quad * 8];
      #pragma unroll
      for (int ni = 0; ni < 4; ni++)
        bf[ni] = *(const bf16x8*)&Bs[(wn * 64 + ni * 16 + lr) * 72 + kc * 32 + quad * 8];
      #pragma unroll
      for (int mi = 0; mi < 4; mi++)
        #pragma unroll
        for (int ni = 0; ni < 4; ni++)
          acc[mi][ni] = __builtin_amdgcn_mfma_f32_16x16x32_bf16(af[mi], bf[ni], acc[mi][ni], 0, 0, 0);
    }
  }
  #pragma unroll
  for (int mi = 0; mi < 4; mi++)
    #pragma unroll
    for (int ni = 0; ni < 4; ni++) {
      int col = n0 + wn * 64 + ni * 16 + lr;
      float bv = bias[col];
      #pragma unroll
      for (int r = 0; r < 4; r++) {
        int row = m0 + wm * 64 + mi * 16 + quad * 4 + r;
        C[(size_t)row * 256 + col] = acc[mi][ni][r] + bv;
      }
    }
}

// ---- conv GEMM: 2048x256xK4096, split-K=4, im2col fused (bf16 x); flat grid 512
__global__ __launch_bounds__(256) void k_conv_sk(const unsigned short* __restrict__ xb,
                                                 const unsigned short* __restrict__ W,
                                                 float* __restrict__ C) {
  __shared__ unsigned short As[64 * 136];
  __shared__ unsigned short Bs[64 * 136];
  const int id = blockIdx.x;
  const int xcd = id & 7, idx = id >> 3;
  const int a = idx >> 2, nt = idx & 3;
  const int ag = xcd * 16 + a;
  const int mt = ag & 31, z = ag >> 5;
  const int m0 = mt * 64, n0 = nt * 64;
  const int kOff = z * 1024;
  C += (size_t)z * 2048 * 256;
  const int tid = threadIdx.x;
  const int wid = tid >> 6, lane = tid & 63;
  const int quad = lane >> 4, lr = lane & 15;
  const int wm = wid >> 1, wn = wid & 1;
  f32x4 acc[2][2] = {};
  for (int kb = 0; kb < 1024; kb += 128) {
    __syncthreads();
    #pragma unroll
    for (int i = 0; i < 4; i++) {
      int c = i * 256 + tid;
      int row = c >> 4, cu = (c & 15) * 8;
      int kk = kOff + kb + cu;
      int m = m0 + row;
      int b = m >> 8, p = m & 255, ph = p >> 4, pw = p & 15;
      int q = kk >> 8, ii = kk & 255;
      int n = (ph * 4 + (q >> 2)) * 64 + pw * 4 + (q & 3);
      *(uint4*)&As[row * 136 + cu] = *(const uint4*)(xb + ((size_t)(b * 4096 + n) * 256 + ii));
      *(uint4*)&Bs[row * 136 + cu] = *(const uint4*)(W + (size_t)(n0 + row) * 4096 + kk);
    }
    __syncthreads();
    #pragma unroll
    for (int kc = 0; kc < 4; kc++) {
      bf16x8 af0 = *(const bf16x8*)&As[(wm * 32 + lr) * 136 + kc * 32 + quad * 8];
      bf16x8 af1 = *(const bf16x8*)&As[(wm * 32 + 16 + lr) * 136 + kc * 32 + quad * 8];
      bf16x8 bf0 = *(const bf16x8*)&Bs[(wn * 32 + lr) * 136 + kc * 32 + quad * 8];
      bf16x8 bf1 = *(const bf16x8*)&Bs[(wn * 32 + 16 + lr) * 136 + kc * 32 + quad * 8];
      acc[0][0] = __builtin_amdgcn_mfma_f32_16x16x32_bf16(af0, bf0, acc[0][0], 0, 0, 0);
      acc[0][1] = __builtin_amdgcn_mfma_f32_16x16x32_bf16(af0, bf1, acc[0][1], 0, 0, 0);
      acc[1][0] = __builtin_amdgcn_mfma_f32_16x16x32_bf16(af1, bf0, acc[1][0], 0, 0, 0);
      acc[1][1] = __builtin_amdgcn_mfma_f32_16x16x32_bf16(af1, bf1, acc[1][1], 0, 0, 0);
    }
  }
  #pragma unroll
  for (int mi = 0; mi < 2; mi++)
    #pragma unroll
    for (int ni = 0; ni < 2; ni++) {
      int col = n0 + wn * 32 + ni * 16 + lr;
      #pragma unroll
      for (int r = 0; r < 4; r++) {
        int row = m0 + wm * 32 + mi * 16 + quad * 4 + r;
        C[(size_t)row * 256 + col] = acc[mi][ni][r];
      }
    }
}

// LayerNorm over C=256; sums 4 split-K conv partials + sr_b first
__global__ __launch_bounds__(256) void k_ln(const float* __restrict__ convp, const float* srb,
                                            const float* g, const float* bb,
                                            unsigned short* __restrict__ xn) {
  int row = blockIdx.x, c = threadIdx.x;
  float v = srb[c];
  #pragma unroll
  for (int s = 0; s < 4; s++) v += convp[s * 524288 + row * 256 + c];
  __shared__ float red[4];
  float s = v;
  #pragma unroll
  for (int d = 1; d < 64; d <<= 1) s += __shfl_xor(s, d, 64);
  if ((c & 63) == 0) red[c >> 6] = s;
  __syncthreads();
  float mu = (red[0] + red[1] + red[2] + red[3]) * (1.f / 256.f);
  __syncthreads();
  float dv = v - mu;
  float s2 = dv * dv;
  #pragma unroll
  for (int d = 1; d < 64; d <<= 1) s2 += __shfl_xor(s2, d, 64);
  if ((c & 63) == 0) red[c >> 6] = s2;
  __syncthreads();
  float var = (red[0] + red[1] + red[2] + red[3]) * (1.f / 256.f);
  float rs = 1.f / sqrtf(var + 1e-5f);
  xn[row * 256 + c] = f2bf(dv * rs * g[c] + bb[c]);
}

// attention pass 1 (R15): swapped QK^T; K staged lane-major in LDS and
// fake-quantized IN STAGING (kqu holds unquantized bf16 k); q fragment
// quantized in-register on load; (wmin,wmax) -> scal[7]/[8] via uint atomics.
__global__ __launch_bounds__(256) void k_attn1(const unsigned short* __restrict__ qq,
                                               const unsigned short* __restrict__ kqu,
                                               float2* __restrict__ rowstats,
                                               float* scal) {
  __shared__ unsigned short KsL[8192];  // 16 KB: [t(16)][lane(64)] x 8 shorts
  __shared__ float red[8];
  const int bh = blockIdx.y;
  const int row0 = blockIdx.x * 256;
  const int tid = threadIdx.x, wid = tid >> 6, lane = tid & 63, quad = lane >> 4, lr = lane & 15;
  const float c2 = 0.17677669529663687f * 1.4426950408889634f;  // 32^-0.5 * log2(e)
  const unsigned short* kb = kqu + (size_t)bh * 8192;
  float dk = scal[5] / 127.f + 1e-8f;
  float idk = 1.f / dk;
  float dq = scal[4] / 127.f + 1e-8f;
  float idq = 1.f / dq;
  #pragma unroll
  for (int k = 0; k < 4; k++) {
    int cid = k * 256 + tid;                 // 1024 chunks of 16B
    int seg = cid >> 6, lc = cid & 63, qc = lc >> 4, lrc = lc & 15;
    uint4 kw = *(const uint4*)(kb + (seg * 16 + lrc) * 32 + qc * 8);
    *(uint4*)&KsL[cid * 8] = qfrag4(kw, idk, dk);
  }
  __syncthreads();
  float wmin = 1e30f, wmax = 0.f;
  #pragma unroll
  for (int g = 0; g < 4; g++) {
    int rowg = row0 + g * 64 + wid * 16 + lr;
    uint4 qw = *(const uint4*)(qq + ((size_t)bh * 4096 + rowg) * 32 + quad * 8);
    bf16x8 qf = qfrag(qw, idq, dq);
    f32x4 acc[16] = {};
    #pragma unroll
    for (int t = 0; t < 16; t++) {
      bf16x8 kf = *(const bf16x8*)&KsL[(t * 64 + quad * 16 + lr) * 8];
      acc[t] = __builtin_amdgcn_mfma_f32_16x16x32_bf16(kf, qf, acc[t], 0, 0, 0);
    }
    float mxr = -1e30f, mnr = 1e30f;
    #pragma unroll
    for (int t = 0; t < 16; t++)
      #pragma unroll
      for (int r = 0; r < 4; r++) {
        float s = acc[t][r];
        mxr = fmaxf(mxr, s); mnr = fminf(mnr, s);
      }
    #pragma unroll
    for (int d = 16; d < 64; d <<= 1) {
      mxr = fmaxf(mxr, __shfl_xor(mxr, d, 64));
      mnr = fminf(mnr, __shfl_xor(mnr, d, 64));
    }
    float m2 = mxr * c2;
    float l = 0.f;
    #pragma unroll
    for (int t = 0; t < 16; t++)
      #pragma unroll
      for (int r = 0; r < 4; r++)
        l += exp2_(fmaf(acc[t][r], c2, -m2));
    #pragma unroll
    for (int d = 16; d < 64; d <<= 1) l += __shfl_xor(l, d, 64);
    float inv_l = 1.f / l;
    if (lane < 16)
      rowstats[(size_t)bh * 4096 + rowg] = make_float2(m2, inv_l);
    wmax = fmaxf(wmax, inv_l);
    wmin = fminf(wmin, exp2_((mnr - mxr) * c2) * inv_l);
  }
  #pragma unroll
  for (int d = 1; d < 16; d <<= 1) {
    wmax = fmaxf(wmax, __shfl_xor(wmax, d, 64));
    wmin = fminf(wmin, __shfl_xor(wmin, d, 64));
  }
  if (lane == 0) { red[wid] = wmin; red[4 + wid] = wmax; }
  __syncthreads();
  if (tid == 0) {
    float mn = fminf(fminf(red[0], red[1]), fminf(red[2], red[3]));
    float mx = fmaxf(fmaxf(red[4], red[5]), fmaxf(red[6], red[7]));
    atomicMin((unsigned*)(scal + 7), __float_as_uint(mn));
    atomicMax((unsigned*)(scal + 8), __float_as_uint(mx));
  }
}

// attention pass 2 (R15): swapped-QK in-register softmax/quant; K/V staged
// lane-major in LDS with fake-quant applied in staging (deterministic,
// bit-identical to attn1's K); q quantized in-register on load.
__global__ __launch_bounds__(256) void k_attn2(const unsigned short* __restrict__ qq,
                                               const unsigned short* __restrict__ kqu,
                                               const unsigned short* __restrict__ vqtu,
                                               const float* scal,
                                               const float2* __restrict__ rowstats,
                                               unsigned short* __restrict__ attn_out) {
  __shared__ unsigned short KsL[8192];  // 16 KB: [t(16)][lane(64)] chunks
  __shared__ unsigned short VsL[8192];  // 16 KB: [ks*2+half(16)][lane(64)] chunks
  const int bh = blockIdx.y, b = bh >> 3, h = bh & 7;
  const int row0 = blockIdx.x * 256;
  const int tid = threadIdx.x, wid = tid >> 6, lane = tid & 63, quad = lane >> 4, lr = lane & 15;
  const float c2 = 0.17677669529663687f * 1.4426950408889634f;
  const unsigned short* kb = kqu + (size_t)bh * 8192;
  const unsigned short* vb = vqtu + (size_t)bh * 8192;
  float dk = scal[5] / 127.f + 1e-8f;
  float idk = 1.f / dk;
  float dv = scal[6] / 127.f + 1e-8f;
  float idv = 1.f / dv;
  float dq = scal[4] / 127.f + 1e-8f;
  float idq = 1.f / dq;
  #pragma unroll
  for (int k = 0; k < 4; k++) {
    int cid = k * 256 + tid;
    int seg = cid >> 6, lc = cid & 63, qc = lc >> 4, lrc = lc & 15;
    uint4 kw = *(const uint4*)(kb + (seg * 16 + lrc) * 32 + qc * 8);
    *(uint4*)&KsL[cid * 8] = qfrag4(kw, idk, dk);
    uint4 vw = *(const uint4*)(vb + ((seg & 1) * 16 + lrc) * 256 + (seg >> 1) * 32 + qc * 8);
    *(uint4*)&VsL[cid * 8] = qfrag4(vw, idv, dv);
  }
  float pmin = scal[7], pmax = scal[8];
  float delta = (pmax - pmin) / 255.f + 1e-8f;
  float zp = rintf(-pmin / delta);
  float qlo = -zp, qhi = 255.f - zp;
  __syncthreads();
  #pragma unroll
  for (int g = 0; g < 4; g++) {
    int rowg = row0 + g * 64 + wid * 16 + lr;
    uint4 qw = *(const uint4*)(qq + ((size_t)bh * 4096 + rowg) * 32 + quad * 8);
    bf16x8 qf = qfrag(qw, idq, dq);
    float2 st = rowstats[(size_t)bh * 4096 + rowg];
    f32x4 acc[16] = {};
    #pragma unroll
    for (int t = 0; t < 16; t++) {
      bf16x8 kf = *(const bf16x8*)&KsL[(t * 64 + quad * 16 + lr) * 8];
      acc[t] = __builtin_amdgcn_mfma_f32_16x16x32_bf16(kf, qf, acc[t], 0, 0, 0);
    }
    float ofs = __log2f(st.y / delta) - st.x;
    f32x4 o0 = {}, o1 = {};
    #pragma unroll
    for (int ks = 0; ks < 8; ks++) {
      float pv[8];
      #pragma unroll
      for (int half = 0; half < 2; half++) {
        #pragma unroll
        for (int r = 0; r < 4; r++) {
          float v = exp2_(fmaf(acc[2 * ks + half][r], c2, ofs));
          pv[half * 4 + r] = fminf(fmaxf(rintf(v), qlo), qhi) * delta;
        }
      }
      unsigned wa = cvtpk(pv[0], pv[1]);
      unsigned wb = cvtpk(pv[2], pv[3]);
      unsigned wc = cvtpk(pv[4], pv[5]);
      unsigned wd = cvtpk(pv[6], pv[7]);
      pl32swap(wa, wc);
      pl16swap(wa, wc);
      pl32swap(wb, wd);
      pl16swap(wb, wd);
      uint4 w = make_uint4(wa, wb, wc, wd);
      bf16x8 pa = *(bf16x8*)&w;
      bf16x8 b0 = *(const bf16x8*)&VsL[((ks * 2 + 0) * 64 + quad * 16 + lr) * 8];
      bf16x8 b1 = *(const bf16x8*)&VsL[((ks * 2 + 1) * 64 + quad * 16 + lr) * 8];
      o0 = __builtin_amdgcn_mfma_f32_16x16x32_bf16(pa, b0, o0, 0, 0, 0);
      o1 = __builtin_amdgcn_mfma_f32_16x16x32_bf16(pa, b1, o1, 0, 0, 0);
    }
    #pragma unroll
    for (int r = 0; r < 4; r++) {
      int n = row0 + g * 64 + wid * 16 + quad * 4 + r;
      size_t base = ((size_t)(b * 4096) + n) * 256 + h * 32;
      attn_out[base + lr] = f2bf(o0[r]);
      attn_out[base + 16 + lr] = f2bf(o1[r]);
    }
  }
}

extern "C" void kernel_launch(void* const* d_in, const int* in_sizes, int n_in,
                              void* d_out, int out_size, void* d_ws, size_t ws_size,
                              hipStream_t stream) {
  const float* x      = (const float*)d_in[0];
  const float* q_w    = (const float*)d_in[1];
  const float* q_b    = (const float*)d_in[2];
  const float* kv_w   = (const float*)d_in[3];
  const float* kv_b   = (const float*)d_in[4];
  const float* sr_w   = (const float*)d_in[5];
  const float* sr_b   = (const float*)d_in[6];
  const float* norm_g = (const float*)d_in[7];
  const float* norm_b = (const float*)d_in[8];
  const float* proj_w = (const float*)d_in[9];
  const float* proj_b = (const float*)d_in[10];
  float* out = (float*)d_out;

  char* ws = (char*)d_ws;
  float* scal = (float*)ws;
  unsigned short* q_wq    = (unsigned short*)(ws + 256);       // 128 KB
  unsigned short* kv_wq   = (unsigned short*)(ws + 131328);    // 256 KB
  unsigned short* proj_wq = (unsigned short*)(ws + 393472);    // 128 KB
  unsigned short* sr_wq   = (unsigned short*)(ws + 524544);    // 2 MB   -> 2621696
  unsigned short* xn      = (unsigned short*)(ws + 2621696);   // 1 MB   -> 3670272
  unsigned short* kqu     = (unsigned short*)(ws + 7864576);   // 1 MB (bf16 k, UNquantized)
  unsigned short* vqtu    = (unsigned short*)(ws + 8913152);   // 1 MB (bf16 v^T, UNquantized)
  float2*         rowstats= (float2*)(ws + 9961728);           // 2 MB   -> 12058880
  float*          convp   = (float*)(ws + 12058880);           // 8 MB (4 partials)
  unsigned short* attn_o  = (unsigned short*)(ws + 12058880);  // over convp (dead after k_ln); 16 MB
  unsigned short* qq      = (unsigned short*)(ws + 45613312);  // 16 MB (bf16 q, UNquantized)
  unsigned short* xb      = (unsigned short*)(ws + 62390528);  // 16 MB (x as bf16)

  k_init<<<1, 64, 0, stream>>>(scal);
  k_absmax4<<<dim3(64, 4), 256, 0, stream>>>(q_w, kv_w, sr_w, proj_w, scal);
  // weight quant + x->bf16 cast
  k_quantw<<<4096, 256, 0, stream>>>(q_w, kv_w, proj_w, sr_w, x,
                                     q_wq, kv_wq, proj_wq, sr_wq, xb, scal);
  // conv GEMM (im2col fused, split-K=4, XCD-swizzled): 2048x256x4096
  k_conv_sk<<<512, 256, 0, stream>>>(xb, sr_wq, convp);
  k_ln<<<2048, 256, 0, stream>>>(convp, sr_b, norm_g, norm_b, xn);
  // FUSED kv-GEMM (256 blocks) + q-GEMM (512 blocks)
  k_gemm_qkv<<<768, 256, 0, stream>>>(xn, kv_wq, kv_b, xb, q_wq, q_b,
                                      kqu, vqtu, qq, scal);
  k_attn1<<<dim3(16, 64), 256, 0, stream>>>(qq, kqu, rowstats, scal);
  k_attn2<<<dim3(16, 64), 256, 0, stream>>>(qq, kqu, vqtu, scal, rowstats, attn_o);
  // proj GEMM: 32768x256x256, 128-tile, XCD-swizzled
  k_gemm128<<<512, 256, 0, stream>>>(attn_o, proj_wq, proj_b, out);
}

// Round 8
// 259.389 us; speedup vs baseline: 1.0689x; 1.0497x over previous
//
#include <hip/hip_runtime.h>
#include <stdint.h>

typedef float f32x4 __attribute__((ext_vector_type(4)));
typedef __bf16 bf16x8 __attribute__((ext_vector_type(8)));

#define DEV __device__ __forceinline__

DEV unsigned short f2bf(float f) {
  unsigned u = __float_as_uint(f);
  u += 0x7FFFu + ((u >> 16) & 1u);   // round-to-nearest-even
  return (unsigned short)(u >> 16);
}

DEV float exp2_(float x) {
#if __has_builtin(__builtin_amdgcn_exp2f)
  return __builtin_amdgcn_exp2f(x);   // raw v_exp_f32; args in [-60,0] => normal range
#else
  return exp2f(x);
#endif
}

// pack two f32 -> one u32 of 2 bf16 (RNE), single instruction
DEV unsigned cvtpk(float lo, float hi) {
  unsigned r;
  asm("v_cvt_pk_bf16_f32 %0, %1, %2" : "=v"(r) : "v"(lo), "v"(hi));
  return r;
}

// a' = {a.lo32, b.lo32}; b' = {a.hi32, b.hi32}
DEV void pl32swap(unsigned &a, unsigned &b) {
#if __has_builtin(__builtin_amdgcn_permlane32_swap)
  auto r = __builtin_amdgcn_permlane32_swap(a, b, false, false);
  a = r[0]; b = r[1];
#else
  asm("v_permlane32_swap_b32 %0, %1" : "+v"(a), "+v"(b));
#endif
}

// rows = 16-lane groups: a' = {a.r0, b.r0, a.r2, b.r2}; b' = {a.r1, b.r1, a.r3, b.r3}
DEV void pl16swap(unsigned &a, unsigned &b) {
#if __has_builtin(__builtin_amdgcn_permlane16_swap)
  auto r = __builtin_amdgcn_permlane16_swap(a, b, false, false);
  a = r[0]; b = r[1];
#else
  asm("v_permlane16_swap_b32 %0, %1" : "+v"(a), "+v"(b));
#endif
}

// symmetric fake-quant of 8 packed bf16 in-register (deterministic: every
// consumer of the same bytes + same delta produces IDENTICAL results).
DEV uint4 qfrag4(uint4 w, float idq, float dq) {
  unsigned o[4];
  const unsigned* wi = &w.x;
  #pragma unroll
  for (int i = 0; i < 4; i++) {
    float lo = __uint_as_float(wi[i] << 16);
    float hi = __uint_as_float(wi[i] & 0xffff0000u);
    lo = fminf(fmaxf(rintf(lo * idq), -128.f), 127.f) * dq;
    hi = fminf(fmaxf(rintf(hi * idq), -128.f), 127.f) * dq;
    o[i] = cvtpk(lo, hi);
  }
  return make_uint4(o[0], o[1], o[2], o[3]);
}

DEV bf16x8 qfrag(uint4 w, float idq, float dq) {
  uint4 r = qfrag4(w, idq, dq);
  return *(bf16x8*)&r;
}

// scal: [0..3]=wmax(q,kv,sr,proj), [4]=qmax, [5]=kmax, [6]=vmax, [7]=pmin, [8]=pmax
__global__ void k_init(float* scal) {
  int t = threadIdx.x;
  if (t < 16) scal[t] = (t == 7) ? __uint_as_float(0x7f800000u) : 0.f;
}

__global__ __launch_bounds__(256) void k_absmax4(const float* w0, const float* w1,
                                                 const float* w2, const float* w3, float* scal) {
  const float* srcs[4] = {w0, w1, w2, w3};
  const int ns[4] = {65536, 131072, 1048576, 65536};
  int t = blockIdx.y;
  const float* src = srcs[t];
  int n = ns[t];
  float m = 0.f;
  for (int i = blockIdx.x * 256 + threadIdx.x; i < n; i += gridDim.x * 256)
    m = fmaxf(m, fabsf(src[i]));
  #pragma unroll
  for (int d = 1; d < 64; d <<= 1) m = fmaxf(m, __shfl_xor(m, d, 64));
  __shared__ float red[4];
  if ((threadIdx.x & 63) == 0) red[threadIdx.x >> 6] = m;
  __syncthreads();
  if (threadIdx.x == 0) {
    m = fmaxf(fmaxf(red[0], red[1]), fmaxf(red[2], red[3]));
    atomicMax((unsigned*)(scal + t), __float_as_uint(m));
  }
}

// fused weight quant + x->bf16 cast, one dispatch (grid.x = 4096):
//   all blocks:  sr_w (1048576 elems) -> sr_wq with im2col-matched k-order
//                x (8388608 f32, 8/thread) -> xb bf16
//   bx < 512:    kv_w (131072)        -> kv_wq   (slot 1)
//   bx < 256:    q_w + proj_w (65536) -> q_wq / proj_wq (slots 0 / 3)
__global__ __launch_bounds__(256) void k_quantw(const float* qw, const float* kvw,
                                                const float* prw, const float* srw,
                                                const float* xf,
                                                unsigned short* qo, unsigned short* kvo,
                                                unsigned short* pro, unsigned short* sro,
                                                unsigned short* xbo,
                                                const float* scal) {
  int bx = blockIdx.x;
  int tid = bx * 256 + threadIdx.x;
  {
    int oo = tid >> 12;
    int rem = tid & 4095;
    int khkw = rem >> 8;
    int i = rem & 255;
    float delta = scal[2] / 127.f + 1e-8f;
    float x = srw[oo * 4096 + i * 16 + khkw];
    sro[tid] = f2bf(fminf(fmaxf(rintf(x / delta), -128.f), 127.f) * delta);
  }
  {
    // x cast: 8 contiguous f32 -> 8 bf16 per thread
    const float4* xs = (const float4*)(xf + (size_t)tid * 8);
    float4 v0 = xs[0], v1 = xs[1];
    unsigned w0 = ((unsigned)f2bf(v0.y) << 16) | f2bf(v0.x);
    unsigned w1 = ((unsigned)f2bf(v0.w) << 16) | f2bf(v0.z);
    unsigned w2 = ((unsigned)f2bf(v1.y) << 16) | f2bf(v1.x);
    unsigned w3 = ((unsigned)f2bf(v1.w) << 16) | f2bf(v1.z);
    *(uint4*)(xbo + (size_t)tid * 8) = make_uint4(w0, w1, w2, w3);
  }
  if (bx < 512) {
    float delta = scal[1] / 127.f + 1e-8f;
    kvo[tid] = f2bf(fminf(fmaxf(rintf(kvw[tid] / delta), -128.f), 127.f) * delta);
  }
  if (bx < 256) {
    float dq = scal[0] / 127.f + 1e-8f;
    qo[tid] = f2bf(fminf(fmaxf(rintf(qw[tid] / dq), -128.f), 127.f) * dq);
    float dp = scal[3] / 127.f + 1e-8f;
    pro[tid] = f2bf(fminf(fmaxf(rintf(prw[tid] / dp), -128.f), 127.f) * dp);
  }
}

// ---- FUSED kv-GEMM + q-GEMM, one dispatch (768 blocks) ----
// blocks [0,256):   kv GEMM 2048x512x256, 64x64 tile, BK=128; writes k and v
//                   UNQUANTIZED bf16 directly in permuted layouts; amax -> scal[5]/[6].
// blocks [256,768): q GEMM 32768x256x256, 128x128 tile, XCD-swizzled; writes
//                   UNQUANTIZED bf16 q permuted into qq[b,h,n,j]; amax -> scal[4].
__global__ __launch_bounds__(256) void k_gemm_qkv(const unsigned short* __restrict__ xnrm,
                                                  const unsigned short* __restrict__ kvw,
                                                  const float* __restrict__ kvb,
                                                  const unsigned short* __restrict__ xb,
                                                  const unsigned short* __restrict__ qw,
                                                  const float* __restrict__ qb,
                                                  unsigned short* __restrict__ kqu,
                                                  unsigned short* __restrict__ vqtu,
                                                  unsigned short* __restrict__ qq,
                                                  float* scal) {
  __shared__ unsigned short smem[18432];  // 36.9 KB union
  const int tid = threadIdx.x;
  const int wid = tid >> 6, lane = tid & 63;
  const int quad = lane >> 4, lr = lane & 15;
  const int wm = wid >> 1, wn = wid & 1;
  if (blockIdx.x < 256) {
    // ---------------- kv GEMM ----------------
    unsigned short* As = smem;            // 64*136
    unsigned short* Bs = smem + 8704;     // 64*136
    const int n0 = (blockIdx.x & 7) * 64, m0 = (blockIdx.x >> 3) * 64;
    f32x4 acc[2][2] = {};
    for (int kb = 0; kb < 256; kb += 128) {
      __syncthreads();
      #pragma unroll
      for (int i = 0; i < 4; i++) {
        int c = i * 256 + tid;
        int row = c >> 4, cu = (c & 15) * 8;
        *(uint4*)&As[row * 136 + cu] = *(const uint4*)(xnrm + (size_t)(m0 + row) * 256 + kb + cu);
        *(uint4*)&Bs[row * 136 + cu] = *(const uint4*)(kvw + (size_t)(n0 + row) * 256 + kb + cu);
      }
      __syncthreads();
      #pragma unroll
      for (int kc = 0; kc < 4; kc++) {
        bf16x8 af0 = *(const bf16x8*)&As[(wm * 32 + lr) * 136 + kc * 32 + quad * 8];
        bf16x8 af1 = *(const bf16x8*)&As[(wm * 32 + 16 + lr) * 136 + kc * 32 + quad * 8];
        bf16x8 bf0 = *(const bf16x8*)&Bs[(wn * 32 + lr) * 136 + kc * 32 + quad * 8];
        bf16x8 bf1 = *(const bf16x8*)&Bs[(wn * 32 + 16 + lr) * 136 + kc * 32 + quad * 8];
        acc[0][0] = __builtin_amdgcn_mfma_f32_16x16x32_bf16(af0, bf0, acc[0][0], 0, 0, 0);
        acc[0][1] = __builtin_amdgcn_mfma_f32_16x16x32_bf16(af0, bf1, acc[0][1], 0, 0, 0);
        acc[1][0] = __builtin_amdgcn_mfma_f32_16x16x32_bf16(af1, bf0, acc[1][0], 0, 0, 0);
        acc[1][1] = __builtin_amdgcn_mfma_f32_16x16x32_bf16(af1, bf1, acc[1][1], 0, 0, 0);
      }
    }
    float amax = 0.f;
    #pragma unroll
    for (int mi = 0; mi < 2; mi++)
      #pragma unroll
      for (int ni = 0; ni < 2; ni++) {
        int col = n0 + wn * 32 + ni * 16 + lr;
        float bv = kvb[col];
        #pragma unroll
        for (int r = 0; r < 4; r++) {
          int row = m0 + wm * 32 + mi * 16 + quad * 4 + r;
          float v = acc[mi][ni][r] + bv;
          int b = row >> 8, n2 = row & 255;
          int h = (col >> 5) & 7, j = col & 31;
          if (col < 256)
            kqu[((size_t)((b * 8 + h) * 256 + n2)) * 32 + j] = f2bf(v);
          else
            vqtu[((size_t)((b * 8 + h) * 32 + j)) * 256 + n2] = f2bf(v);
          amax = fmaxf(amax, fabsf(v));
        }
      }
    #pragma unroll
    for (int d = 1; d < 64; d <<= 1) amax = fmaxf(amax, __shfl_xor(amax, d, 64));
    if (lane == 0)
      atomicMax((unsigned*)(scal + 5 + (n0 >= 256 ? 1 : 0)), __float_as_uint(amax));
  } else {
    // ---------------- q GEMM (XCD-swizzled 128x128) ----------------
    unsigned short* As = smem;            // 128*72
    unsigned short* Bs = smem + 9216;     // 128*72
    const int id = blockIdx.x - 256;
    const int xcd = id & 7, idx = id >> 3;          // 64 blocks per XCD
    const int mt = xcd * 32 + (idx >> 1), nt = idx & 1;
    const int m0 = mt * 128, n0 = nt * 128;
    f32x4 acc[4][4] = {};
    for (int kb = 0; kb < 256; kb += 64) {
      __syncthreads();
      #pragma unroll
      for (int i = 0; i < 4; i++) {
        int c = i * 256 + tid;
        int row = c >> 3, cu = (c & 7) * 8;
        *(uint4*)&As[row * 72 + cu] = *(const uint4*)(xb + (size_t)(m0 + row) * 256 + kb + cu);
        *(uint4*)&Bs[row * 72 + cu] = *(const uint4*)(qw + (size_t)(n0 + row) * 256 + kb + cu);
      }
      __syncthreads();
      #pragma unroll
      for (int kc = 0; kc < 2; kc++) {
        bf16x8 af[4], bf[4];
        #pragma unroll
        for (int mi = 0; mi < 4; mi++)
          af[mi] = *(const bf16x8*)&As[(wm * 64 + mi * 16 + lr) * 72 + kc * 32 + quad * 8];
        #pragma unroll
        for (int ni = 0; ni < 4; ni++)
          bf[ni] = *(const bf16x8*)&Bs[(wn * 64 + ni * 16 + lr) * 72 + kc * 32 + quad * 8];
        #pragma unroll
        for (int mi = 0; mi < 4; mi++)
          #pragma unroll
          for (int ni = 0; ni < 4; ni++)
            acc[mi][ni] = __builtin_amdgcn_mfma_f32_16x16x32_bf16(af[mi], bf[ni], acc[mi][ni], 0, 0, 0);
      }
    }
    float amax = 0.f;
    #pragma unroll
    for (int mi = 0; mi < 4; mi++)
      #pragma unroll
      for (int ni = 0; ni < 4; ni++) {
        int col = n0 + wn * 64 + ni * 16 + lr;
        float bv = qb[col];
        #pragma unroll
        for (int r = 0; r < 4; r++) {
          int row = m0 + wm * 64 + mi * 16 + quad * 4 + r;
          float v = acc[mi][ni][r] + bv;
          int b = row >> 12, nn = row & 4095;
          int h = col >> 5, j = col & 31;
          qq[((size_t)(b * 8 + h) * 4096 + nn) * 32 + j] = f2bf(v);
          amax = fmaxf(amax, fabsf(v));
        }
      }
    #pragma unroll
    for (int d = 1; d < 64; d <<= 1) amax = fmaxf(amax, __shfl_xor(amax, d, 64));
    if (lane == 0) atomicMax((unsigned*)(scal + 4), __float_as_uint(amax));
  }
}

// ---- 128x128-tile GEMM (proj): f32 C out, XCD-swizzled ----
__global__ __launch_bounds__(256) void k_gemm128(const unsigned short* __restrict__ Ab,
                                                 const unsigned short* __restrict__ W,
                                                 const float* __restrict__ bias,
                                                 float* __restrict__ C) {
  __shared__ unsigned short As[128 * 72];
  __shared__ unsigned short Bs[128 * 72];
  const int id = blockIdx.x;
  const int xcd = id & 7, idx = id >> 3;
  const int mt = xcd * 32 + (idx >> 1), nt = idx & 1;
  const int m0 = mt * 128, n0 = nt * 128;
  const int tid = threadIdx.x;
  const int wid = tid >> 6, lane = tid & 63;
  const int quad = lane >> 4, lr = lane & 15;
  const int wm = wid >> 1, wn = wid & 1;
  f32x4 acc[4][4] = {};
  for (int kb = 0; kb < 256; kb += 64) {
    __syncthreads();
    #pragma unroll
    for (int i = 0; i < 4; i++) {
      int c = i * 256 + tid;
      int row = c >> 3, cu = (c & 7) * 8;
      *(uint4*)&As[row * 72 + cu] = *(const uint4*)(Ab + (size_t)(m0 + row) * 256 + kb + cu);
      *(uint4*)&Bs[row * 72 + cu] = *(const uint4*)(W + (size_t)(n0 + row) * 256 + kb + cu);
    }
    __syncthreads();
    #pragma unroll
    for (int kc = 0; kc < 2; kc++) {
      bf16x8 af[4], bf[4];
      #pragma unroll
      for (int mi = 0; mi < 4; mi++)
        af[mi] = *(const bf16x8*)&As[(wm * 64 + mi * 16 + lr) * 72 + kc * 32 + quad * 8];
      #pragma unroll
      for (int ni = 0; ni < 4; ni++)
        bf[ni] = *(const bf16x8*)&Bs[(wn * 64 + ni * 16 + lr) * 72 + kc * 32 + quad * 8];
      #pragma unroll
      for (int mi = 0; mi < 4; mi++)
        #pragma unroll
        for (int ni = 0; ni < 4; ni++)
          acc[mi][ni] = __builtin_amdgcn_mfma_f32_16x16x32_bf16(af[mi], bf[ni], acc[mi][ni], 0, 0, 0);
    }
  }
  #pragma unroll
  for (int mi = 0; mi < 4; mi++)
    #pragma unroll
    for (int ni = 0; ni < 4; ni++) {
      int col = n0 + wn * 64 + ni * 16 + lr;
      float bv = bias[col];
      #pragma unroll
      for (int r = 0; r < 4; r++) {
        int row = m0 + wm * 64 + mi * 16 + quad * 4 + r;
        C[(size_t)row * 256 + col] = acc[mi][ni][r] + bv;
      }
    }
}

// ---- conv GEMM: 2048x256xK4096, split-K=4, im2col fused (bf16 x); flat grid 512
__global__ __launch_bounds__(256) void k_conv_sk(const unsigned short* __restrict__ xb,
                                                 const unsigned short* __restrict__ W,
                                                 float* __restrict__ C) {
  __shared__ unsigned short As[64 * 136];
  __shared__ unsigned short Bs[64 * 136];
  const int id = blockIdx.x;
  const int xcd = id & 7, idx = id >> 3;
  const int a = idx >> 2, nt = idx & 3;
  const int ag = xcd * 16 + a;
  const int mt = ag & 31, z = ag >> 5;
  const int m0 = mt * 64, n0 = nt * 64;
  const int kOff = z * 1024;
  C += (size_t)z * 2048 * 256;
  const int tid = threadIdx.x;
  const int wid = tid >> 6, lane = tid & 63;
  const int quad = lane >> 4, lr = lane & 15;
  const int wm = wid >> 1, wn = wid & 1;
  f32x4 acc[2][2] = {};
  for (int kb = 0; kb < 1024; kb += 128) {
    __syncthreads();
    #pragma unroll
    for (int i = 0; i < 4; i++) {
      int c = i * 256 + tid;
      int row = c >> 4, cu = (c & 15) * 8;
      int kk = kOff + kb + cu;
      int m = m0 + row;
      int b = m >> 8, p = m & 255, ph = p >> 4, pw = p & 15;
      int q = kk >> 8, ii = kk & 255;
      int n = (ph * 4 + (q >> 2)) * 64 + pw * 4 + (q & 3);
      *(uint4*)&As[row * 136 + cu] = *(const uint4*)(xb + ((size_t)(b * 4096 + n) * 256 + ii));
      *(uint4*)&Bs[row * 136 + cu] = *(const uint4*)(W + (size_t)(n0 + row) * 4096 + kk);
    }
    __syncthreads();
    #pragma unroll
    for (int kc = 0; kc < 4; kc++) {
      bf16x8 af0 = *(const bf16x8*)&As[(wm * 32 + lr) * 136 + kc * 32 + quad * 8];
      bf16x8 af1 = *(const bf16x8*)&As[(wm * 32 + 16 + lr) * 136 + kc * 32 + quad * 8];
      bf16x8 bf0 = *(const bf16x8*)&Bs[(wn * 32 + lr) * 136 + kc * 32 + quad * 8];
      bf16x8 bf1 = *(const bf16x8*)&Bs[(wn * 32 + 16 + lr) * 136 + kc * 32 + quad * 8];
      acc[0][0] = __builtin_amdgcn_mfma_f32_16x16x32_bf16(af0, bf0, acc[0][0], 0, 0, 0);
      acc[0][1] = __builtin_amdgcn_mfma_f32_16x16x32_bf16(af0, bf1, acc[0][1], 0, 0, 0);
      acc[1][0] = __builtin_amdgcn_mfma_f32_16x16x32_bf16(af1, bf0, acc[1][0], 0, 0, 0);
      acc[1][1] = __builtin_amdgcn_mfma_f32_16x16x32_bf16(af1, bf1, acc[1][1], 0, 0, 0);
    }
  }
  #pragma unroll
  for (int mi = 0; mi < 2; mi++)
    #pragma unroll
    for (int ni = 0; ni < 2; ni++) {
      int col = n0 + wn * 32 + ni * 16 + lr;
      #pragma unroll
      for (int r = 0; r < 4; r++) {
        int row = m0 + wm * 32 + mi * 16 + quad * 4 + r;
        C[(size_t)row * 256 + col] = acc[mi][ni][r];
      }
    }
}

// LayerNorm over C=256; sums 4 split-K conv partials + sr_b first
__global__ __launch_bounds__(256) void k_ln(const float* __restrict__ convp, const float* srb,
                                            const float* g, const float* bb,
                                            unsigned short* __restrict__ xn) {
  int row = blockIdx.x, c = threadIdx.x;
  float v = srb[c];
  #pragma unroll
  for (int s = 0; s < 4; s++) v += convp[s * 524288 + row * 256 + c];
  __shared__ float red[4];
  float s = v;
  #pragma unroll
  for (int d = 1; d < 64; d <<= 1) s += __shfl_xor(s, d, 64);
  if ((c & 63) == 0) red[c >> 6] = s;
  __syncthreads();
  float mu = (red[0] + red[1] + red[2] + red[3]) * (1.f / 256.f);
  __syncthreads();
  float dv = v - mu;
  float s2 = dv * dv;
  #pragma unroll
  for (int d = 1; d < 64; d <<= 1) s2 += __shfl_xor(s2, d, 64);
  if ((c & 63) == 0) red[c >> 6] = s2;
  __syncthreads();
  float var = (red[0] + red[1] + red[2] + red[3]) * (1.f / 256.f);
  float rs = 1.f / sqrtf(var + 1e-5f);
  xn[row * 256 + c] = f2bf(dv * rs * g[c] + bb[c]);
}

// attention pass 1 (R16): swapped QK^T; K staged lane-major + fake-quant in
// staging; q quantized in-register. NO atomics to scal (read/atomic line
// conflict caused a 62us stall in R15): per-block (wmin,wmax) -> pstat.
// Grid 32x64 (2 row-groups/block) for 8 blocks/CU latency hiding.
__global__ __launch_bounds__(256) void k_attn1(const unsigned short* __restrict__ qq,
                                               const unsigned short* __restrict__ kqu,
                                               float2* __restrict__ rowstats,
                                               const float* __restrict__ scal,
                                               float2* __restrict__ pstat) {
  __shared__ unsigned short KsL[8192];  // 16 KB: [t(16)][lane(64)] x 8 shorts
  __shared__ float red[8];
  const int bh = blockIdx.y;
  const int row0 = blockIdx.x * 128;
  const int tid = threadIdx.x, wid = tid >> 6, lane = tid & 63, quad = lane >> 4, lr = lane & 15;
  const float c2 = 0.17677669529663687f * 1.4426950408889634f;  // 32^-0.5 * log2(e)
  const unsigned short* kb = kqu + (size_t)bh * 8192;
  float dk = scal[5] / 127.f + 1e-8f;
  float idk = 1.f / dk;
  float dq = scal[4] / 127.f + 1e-8f;
  float idq = 1.f / dq;
  #pragma unroll
  for (int k = 0; k < 4; k++) {
    int cid = k * 256 + tid;                 // 1024 chunks of 16B
    int seg = cid >> 6, lc = cid & 63, qc = lc >> 4, lrc = lc & 15;
    uint4 kw = *(const uint4*)(kb + (seg * 16 + lrc) * 32 + qc * 8);
    *(uint4*)&KsL[cid * 8] = qfrag4(kw, idk, dk);
  }
  __syncthreads();
  float wmin = 1e30f, wmax = 0.f;
  #pragma unroll
  for (int g = 0; g < 2; g++) {
    int rowg = row0 + g * 64 + wid * 16 + lr;
    uint4 qw = *(const uint4*)(qq + ((size_t)bh * 4096 + rowg) * 32 + quad * 8);
    bf16x8 qf = qfrag(qw, idq, dq);
    f32x4 acc[16] = {};
    #pragma unroll
    for (int t = 0; t < 16; t++) {
      bf16x8 kf = *(const bf16x8*)&KsL[(t * 64 + quad * 16 + lr) * 8];
      acc[t] = __builtin_amdgcn_mfma_f32_16x16x32_bf16(kf, qf, acc[t], 0, 0, 0);
    }
    float mxr = -1e30f, mnr = 1e30f;
    #pragma unroll
    for (int t = 0; t < 16; t++)
      #pragma unroll
      for (int r = 0; r < 4; r++) {
        float s = acc[t][r];
        mxr = fmaxf(mxr, s); mnr = fminf(mnr, s);
      }
    #pragma unroll
    for (int d = 16; d < 64; d <<= 1) {
      mxr = fmaxf(mxr, __shfl_xor(mxr, d, 64));
      mnr = fminf(mnr, __shfl_xor(mnr, d, 64));
    }
    float m2 = mxr * c2;
    float l = 0.f;
    #pragma unroll
    for (int t = 0; t < 16; t++)
      #pragma unroll
      for (int r = 0; r < 4; r++)
        l += exp2_(fmaf(acc[t][r], c2, -m2));
    #pragma unroll
    for (int d = 16; d < 64; d <<= 1) l += __shfl_xor(l, d, 64);
    float inv_l = 1.f / l;
    if (lane < 16)
      rowstats[(size_t)bh * 4096 + rowg] = make_float2(m2, inv_l);
    wmax = fmaxf(wmax, inv_l);
    wmin = fminf(wmin, exp2_((mnr - mxr) * c2) * inv_l);
  }
  #pragma unroll
  for (int d = 1; d < 16; d <<= 1) {
    wmax = fmaxf(wmax, __shfl_xor(wmax, d, 64));
    wmin = fminf(wmin, __shfl_xor(wmin, d, 64));
  }
  if (lane == 0) { red[wid] = wmin; red[4 + wid] = wmax; }
  __syncthreads();
  if (tid == 0) {
    float mn = fminf(fminf(red[0], red[1]), fminf(red[2], red[3]));
    float mx = fmaxf(fmaxf(red[4], red[5]), fmaxf(red[6], red[7]));
    pstat[blockIdx.y * 32 + blockIdx.x] = make_float2(mn, mx);
  }
}

// reduce pstat[2048] -> scal[7]=pmin, scal[8]=pmax  (single block)
__global__ __launch_bounds__(256) void k_pminmax(const float2* __restrict__ pstat, float* scal) {
  int t = threadIdx.x;
  float mn = 1e30f, mx = 0.f;
  #pragma unroll
  for (int i = 0; i < 8; i++) {
    float2 v = pstat[t + i * 256];
    mn = fminf(mn, v.x); mx = fmaxf(mx, v.y);
  }
  #pragma unroll
  for (int d = 1; d < 64; d <<= 1) {
    mn = fminf(mn, __shfl_xor(mn, d, 64));
    mx = fmaxf(mx, __shfl_xor(mx, d, 64));
  }
  __shared__ float red[8];
  if ((t & 63) == 0) { red[t >> 6] = mn; red[4 + (t >> 6)] = mx; }
  __syncthreads();
  if (t == 0) {
    scal[7] = fminf(fminf(red[0], red[1]), fminf(red[2], red[3]));
    scal[8] = fmaxf(fmaxf(red[4], red[5]), fmaxf(red[6], red[7]));
  }
}

// attention pass 2 (R16 = R15 structure): swapped-QK in-register softmax/quant;
// K/V staged lane-major with fake-quant in staging; q quantized on load.
__global__ __launch_bounds__(256) void k_attn2(const unsigned short* __restrict__ qq,
                                               const unsigned short* __restrict__ kqu,
                                               const unsigned short* __restrict__ vqtu,
                                               const float* __restrict__ scal,
                                               const float2* __restrict__ rowstats,
                                               unsigned short* __restrict__ attn_out) {
  __shared__ unsigned short KsL[8192];  // 16 KB: [t(16)][lane(64)] chunks
  __shared__ unsigned short VsL[8192];  // 16 KB: [ks*2+half(16)][lane(64)] chunks
  const int bh = blockIdx.y, b = bh >> 3, h = bh & 7;
  const int row0 = blockIdx.x * 256;
  const int tid = threadIdx.x, wid = tid >> 6, lane = tid & 63, quad = lane >> 4, lr = lane & 15;
  const float c2 = 0.17677669529663687f * 1.4426950408889634f;
  const unsigned short* kb = kqu + (size_t)bh * 8192;
  const unsigned short* vb = vqtu + (size_t)bh * 8192;
  float dk = scal[5] / 127.f + 1e-8f;
  float idk = 1.f / dk;
  float dv = scal[6] / 127.f + 1e-8f;
  float idv = 1.f / dv;
  float dq = scal[4] / 127.f + 1e-8f;
  float idq = 1.f / dq;
  #pragma unroll
  for (int k = 0; k < 4; k++) {
    int cid = k * 256 + tid;
    int seg = cid >> 6, lc = cid & 63, qc = lc >> 4, lrc = lc & 15;
    uint4 kw = *(const uint4*)(kb + (seg * 16 + lrc) * 32 + qc * 8);
    *(uint4*)&KsL[cid * 8] = qfrag4(kw, idk, dk);
    uint4 vw = *(const uint4*)(vb + ((seg & 1) * 16 + lrc) * 256 + (seg >> 1) * 32 + qc * 8);
    *(uint4*)&VsL[cid * 8] = qfrag4(vw, idv, dv);
  }
  float pmin = scal[7], pmax = scal[8];
  float delta = (pmax - pmin) / 255.f + 1e-8f;
  float zp = rintf(-pmin / delta);
  float qlo = -zp, qhi = 255.f - zp;
  __syncthreads();
  #pragma unroll
  for (int g = 0; g < 4; g++) {
    int rowg = row0 + g * 64 + wid * 16 + lr;
    uint4 qw = *(const uint4*)(qq + ((size_t)bh * 4096 + rowg) * 32 + quad * 8);
    bf16x8 qf = qfrag(qw, idq, dq);
    float2 st = rowstats[(size_t)bh * 4096 + rowg];
    f32x4 acc[16] = {};
    #pragma unroll
    for (int t = 0; t < 16; t++) {
      bf16x8 kf = *(const bf16x8*)&KsL[(t * 64 + quad * 16 + lr) * 8];
      acc[t] = __builtin_amdgcn_mfma_f32_16x16x32_bf16(kf, qf, acc[t], 0, 0, 0);
    }
    float ofs = __log2f(st.y / delta) - st.x;
    f32x4 o0 = {}, o1 = {};
    #pragma unroll
    for (int ks = 0; ks < 8; ks++) {
      float pv[8];
      #pragma unroll
      for (int half = 0; half < 2; half++) {
        #pragma unroll
        for (int r = 0; r < 4; r++) {
          float v = exp2_(fmaf(acc[2 * ks + half][r], c2, ofs));
          pv[half * 4 + r] = fminf(fmaxf(rintf(v), qlo), qhi) * delta;
        }
      }
      unsigned wa = cvtpk(pv[0], pv[1]);
      unsigned wb = cvtpk(pv[2], pv[3]);
      unsigned wc = cvtpk(pv[4], pv[5]);
      unsigned wd = cvtpk(pv[6], pv[7]);
      pl32swap(wa, wc);
      pl16swap(wa, wc);
      pl32swap(wb, wd);
      pl16swap(wb, wd);
      uint4 w = make_uint4(wa, wb, wc, wd);
      bf16x8 pa = *(bf16x8*)&w;
      bf16x8 b0 = *(const bf16x8*)&VsL[((ks * 2 + 0) * 64 + quad * 16 + lr) * 8];
      bf16x8 b1 = *(const bf16x8*)&VsL[((ks * 2 + 1) * 64 + quad * 16 + lr) * 8];
      o0 = __builtin_amdgcn_mfma_f32_16x16x32_bf16(pa, b0, o0, 0, 0, 0);
      o1 = __builtin_amdgcn_mfma_f32_16x16x32_bf16(pa, b1, o1, 0, 0, 0);
    }
    #pragma unroll
    for (int r = 0; r < 4; r++) {
      int n = row0 + g * 64 + wid * 16 + quad * 4 + r;
      size_t base = ((size_t)(b * 4096) + n) * 256 + h * 32;
      attn_out[base + lr] = f2bf(o0[r]);
      attn_out[base + 16 + lr] = f2bf(o1[r]);
    }
  }
}

extern "C" void kernel_launch(void* const* d_in, const int* in_sizes, int n_in,
                              void* d_out, int out_size, void* d_ws, size_t ws_size,
                              hipStream_t stream) {
  const float* x      = (const float*)d_in[0];
  const float* q_w    = (const float*)d_in[1];
  const float* q_b    = (const float*)d_in[2];
  const float* kv_w   = (const float*)d_in[3];
  const float* kv_b   = (const float*)d_in[4];
  const float* sr_w   = (const float*)d_in[5];
  const float* sr_b   = (const float*)d_in[6];
  const float* norm_g = (const float*)d_in[7];
  const float* norm_b = (const float*)d_in[8];
  const float* proj_w = (const float*)d_in[9];
  const float* proj_b = (const float*)d_in[10];
  float* out = (float*)d_out;

  char* ws = (char*)d_ws;
  float* scal = (float*)ws;
  unsigned short* q_wq    = (unsigned short*)(ws + 256);       // 128 KB
  unsigned short* kv_wq   = (unsigned short*)(ws + 131328);    // 256 KB
  unsigned short* proj_wq = (unsigned short*)(ws + 393472);    // 128 KB
  unsigned short* sr_wq   = (unsigned short*)(ws + 524544);    // 2 MB   -> 2621696
  unsigned short* xn      = (unsigned short*)(ws + 2621696);   // 1 MB   -> 3670272
  unsigned short* kqu     = (unsigned short*)(ws + 7864576);   // 1 MB (bf16 k, UNquantized)
  unsigned short* vqtu    = (unsigned short*)(ws + 8913152);   // 1 MB (bf16 v^T, UNquantized)
  float2*         rowstats= (float2*)(ws + 9961728);           // 2 MB   -> 12058880
  float*          convp   = (float*)(ws + 12058880);           // 8 MB (4 partials)
  unsigned short* attn_o  = (unsigned short*)(ws + 12058880);  // over convp (dead after k_ln); 16 MB
  float2*         pstat   = (float2*)(ws + 28836096);          // 16 KB
  unsigned short* qq      = (unsigned short*)(ws + 45613312);  // 16 MB (bf16 q, UNquantized)
  unsigned short* xb      = (unsigned short*)(ws + 62390528);  // 16 MB (x as bf16)

  k_init<<<1, 64, 0, stream>>>(scal);
  k_absmax4<<<dim3(64, 4), 256, 0, stream>>>(q_w, kv_w, sr_w, proj_w, scal);
  // weight quant + x->bf16 cast
  k_quantw<<<4096, 256, 0, stream>>>(q_w, kv_w, proj_w, sr_w, x,
                                     q_wq, kv_wq, proj_wq, sr_wq, xb, scal);
  // conv GEMM (im2col fused, split-K=4, XCD-swizzled): 2048x256x4096
  k_conv_sk<<<512, 256, 0, stream>>>(xb, sr_wq, convp);
  k_ln<<<2048, 256, 0, stream>>>(convp, sr_b, norm_g, norm_b, xn);
  // FUSED kv-GEMM (256 blocks) + q-GEMM (512 blocks)
  k_gemm_qkv<<<768, 256, 0, stream>>>(xn, kv_wq, kv_b, xb, q_wq, q_b,
                                      kqu, vqtu, qq, scal);
  k_attn1<<<dim3(32, 64), 256, 0, stream>>>(qq, kqu, rowstats, scal, pstat);
  k_pminmax<<<1, 256, 0, stream>>>(pstat, scal);
  k_attn2<<<dim3(16, 64), 256, 0, stream>>>(qq, kqu, vqtu, scal, rowstats, attn_o);
  // proj GEMM: 32768x256x256, 128-tile, XCD-swizzled
  k_gemm128<<<512, 256, 0, stream>>>(attn_o, proj_wq, proj_b, out);
}

// Round 9
// 234.956 us; speedup vs baseline: 1.1801x; 1.1040x over previous
//
#include <hip/hip_runtime.h>
#include <stdint.h>

typedef float f32x4 __attribute__((ext_vector_type(4)));
typedef __bf16 bf16x8 __attribute__((ext_vector_type(8)));

#define DEV __device__ __forceinline__

DEV unsigned short f2bf(float f) {
  unsigned u = __float_as_uint(f);
  u += 0x7FFFu + ((u >> 16) & 1u);   // round-to-nearest-even
  return (unsigned short)(u >> 16);
}

DEV float exp2_(float x) {
#if __has_builtin(__builtin_amdgcn_exp2f)
  return __builtin_amdgcn_exp2f(x);   // raw v_exp_f32; args in [-60,0] => normal range
#else
  return exp2f(x);
#endif
}

// pack two f32 -> one u32 of 2 bf16 (RNE), single instruction
DEV unsigned cvtpk(float lo, float hi) {
  unsigned r;
  asm("v_cvt_pk_bf16_f32 %0, %1, %2" : "=v"(r) : "v"(lo), "v"(hi));
  return r;
}

// a' = {a.lo32, b.lo32}; b' = {a.hi32, b.hi32}
DEV void pl32swap(unsigned &a, unsigned &b) {
#if __has_builtin(__builtin_amdgcn_permlane32_swap)
  auto r = __builtin_amdgcn_permlane32_swap(a, b, false, false);
  a = r[0]; b = r[1];
#else
  asm("v_permlane32_swap_b32 %0, %1" : "+v"(a), "+v"(b));
#endif
}

// rows = 16-lane groups: a' = {a.r0, b.r0, a.r2, b.r2}; b' = {a.r1, b.r1, a.r3, b.r3}
DEV void pl16swap(unsigned &a, unsigned &b) {
#if __has_builtin(__builtin_amdgcn_permlane16_swap)
  auto r = __builtin_amdgcn_permlane16_swap(a, b, false, false);
  a = r[0]; b = r[1];
#else
  asm("v_permlane16_swap_b32 %0, %1" : "+v"(a), "+v"(b));
#endif
}

// symmetric fake-quant of 8 packed bf16 in-register (deterministic: every
// consumer of the same bytes + same delta produces IDENTICAL results).
DEV uint4 qfrag4(uint4 w, float idq, float dq) {
  unsigned o[4];
  const unsigned* wi = &w.x;
  #pragma unroll
  for (int i = 0; i < 4; i++) {
    float lo = __uint_as_float(wi[i] << 16);
    float hi = __uint_as_float(wi[i] & 0xffff0000u);
    lo = fminf(fmaxf(rintf(lo * idq), -128.f), 127.f) * dq;
    hi = fminf(fmaxf(rintf(hi * idq), -128.f), 127.f) * dq;
    o[i] = cvtpk(lo, hi);
  }
  return make_uint4(o[0], o[1], o[2], o[3]);
}

DEV bf16x8 qfrag(uint4 w, float idq, float dq) {
  uint4 r = qfrag4(w, idq, dq);
  return *(bf16x8*)&r;
}

// scal: [0..3]=wmax(q,kv,sr,proj), [4]=qmax, [5]=kmax, [6]=vmax, [7]=pmin, [8]=pmax
// (no k_init needed: every slot is plainly written by a reducer before use)

// per-weight absmax partials: NO atomics (same-line atomic storms cost ~40us,
// R15/R16 evidence). Block (bx, t) writes wred[t*64 + bx].
__global__ __launch_bounds__(256) void k_absmax4(const float* w0, const float* w1,
                                                 const float* w2, const float* w3,
                                                 float* wred) {
  const float* srcs[4] = {w0, w1, w2, w3};
  const int ns[4] = {65536, 131072, 1048576, 65536};
  int t = blockIdx.y;
  const float* src = srcs[t];
  int n = ns[t];
  float m = 0.f;
  for (int i = blockIdx.x * 256 + threadIdx.x; i < n; i += gridDim.x * 256)
    m = fmaxf(m, fabsf(src[i]));
  #pragma unroll
  for (int d = 1; d < 64; d <<= 1) m = fmaxf(m, __shfl_xor(m, d, 64));
  __shared__ float red[4];
  if ((threadIdx.x & 63) == 0) red[threadIdx.x >> 6] = m;
  __syncthreads();
  if (threadIdx.x == 0) {
    m = fmaxf(fmaxf(red[0], red[1]), fmaxf(red[2], red[3]));
    wred[t * 64 + blockIdx.x] = m;
  }
}

// reduce wred[4][64] -> scal[0..3]; wave w handles weight w (64 partials)
__global__ __launch_bounds__(256) void k_redW(const float* __restrict__ wred, float* scal) {
  int t = threadIdx.x;
  float v = wred[t];
  #pragma unroll
  for (int d = 1; d < 64; d <<= 1) v = fmaxf(v, __shfl_xor(v, d, 64));
  if ((t & 63) == 0) scal[t >> 6] = v;
}

// fused weight quant + x->bf16 cast, one dispatch (grid.x = 4096):
//   all blocks:  sr_w (1048576 elems) -> sr_wq with im2col-matched k-order
//                x (8388608 f32, 8/thread) -> xb bf16
//   bx < 512:    kv_w (131072)        -> kv_wq   (slot 1)
//   bx < 256:    q_w + proj_w (65536) -> q_wq / proj_wq (slots 0 / 3)
__global__ __launch_bounds__(256) void k_quantw(const float* qw, const float* kvw,
                                                const float* prw, const float* srw,
                                                const float* xf,
                                                unsigned short* qo, unsigned short* kvo,
                                                unsigned short* pro, unsigned short* sro,
                                                unsigned short* xbo,
                                                const float* scal) {
  int bx = blockIdx.x;
  int tid = bx * 256 + threadIdx.x;
  {
    int oo = tid >> 12;
    int rem = tid & 4095;
    int khkw = rem >> 8;
    int i = rem & 255;
    float delta = scal[2] / 127.f + 1e-8f;
    float x = srw[oo * 4096 + i * 16 + khkw];
    sro[tid] = f2bf(fminf(fmaxf(rintf(x / delta), -128.f), 127.f) * delta);
  }
  {
    // x cast: 8 contiguous f32 -> 8 bf16 per thread
    const float4* xs = (const float4*)(xf + (size_t)tid * 8);
    float4 v0 = xs[0], v1 = xs[1];
    unsigned w0 = ((unsigned)f2bf(v0.y) << 16) | f2bf(v0.x);
    unsigned w1 = ((unsigned)f2bf(v0.w) << 16) | f2bf(v0.z);
    unsigned w2 = ((unsigned)f2bf(v1.y) << 16) | f2bf(v1.x);
    unsigned w3 = ((unsigned)f2bf(v1.w) << 16) | f2bf(v1.z);
    *(uint4*)(xbo + (size_t)tid * 8) = make_uint4(w0, w1, w2, w3);
  }
  if (bx < 512) {
    float delta = scal[1] / 127.f + 1e-8f;
    kvo[tid] = f2bf(fminf(fmaxf(rintf(kvw[tid] / delta), -128.f), 127.f) * delta);
  }
  if (bx < 256) {
    float dq = scal[0] / 127.f + 1e-8f;
    qo[tid] = f2bf(fminf(fmaxf(rintf(qw[tid] / dq), -128.f), 127.f) * dq);
    float dp = scal[3] / 127.f + 1e-8f;
    pro[tid] = f2bf(fminf(fmaxf(rintf(prw[tid] / dp), -128.f), 127.f) * dp);
  }
}

// ---- FUSED kv-GEMM + q-GEMM, one dispatch (768 blocks) ----
// blocks [0,256):   kv GEMM 2048x512x256, 64x64 tile, BK=128; writes k and v
//                   UNQUANTIZED bf16 directly in permuted layouts.
// blocks [256,768): q GEMM 32768x256x256, 128x128 tile, XCD-swizzled; writes
//                   UNQUANTIZED bf16 q permuted into qq[b,h,n,j].
// Per-wave amax -> wredG[bid*4+wid] (plain stores; NO same-line atomics).
__global__ __launch_bounds__(256) void k_gemm_qkv(const unsigned short* __restrict__ xnrm,
                                                  const unsigned short* __restrict__ kvw,
                                                  const float* __restrict__ kvb,
                                                  const unsigned short* __restrict__ xb,
                                                  const unsigned short* __restrict__ qw,
                                                  const float* __restrict__ qb,
                                                  unsigned short* __restrict__ kqu,
                                                  unsigned short* __restrict__ vqtu,
                                                  unsigned short* __restrict__ qq,
                                                  float* __restrict__ wredG) {
  __shared__ unsigned short smem[18432];  // 36.9 KB union
  const int tid = threadIdx.x;
  const int wid = tid >> 6, lane = tid & 63;
  const int quad = lane >> 4, lr = lane & 15;
  const int wm = wid >> 1, wn = wid & 1;
  if (blockIdx.x < 256) {
    // ---------------- kv GEMM ----------------
    unsigned short* As = smem;            // 64*136
    unsigned short* Bs = smem + 8704;     // 64*136
    const int n0 = (blockIdx.x & 7) * 64, m0 = (blockIdx.x >> 3) * 64;
    f32x4 acc[2][2] = {};
    for (int kb = 0; kb < 256; kb += 128) {
      __syncthreads();
      #pragma unroll
      for (int i = 0; i < 4; i++) {
        int c = i * 256 + tid;
        int row = c >> 4, cu = (c & 15) * 8;
        *(uint4*)&As[row * 136 + cu] = *(const uint4*)(xnrm + (size_t)(m0 + row) * 256 + kb + cu);
        *(uint4*)&Bs[row * 136 + cu] = *(const uint4*)(kvw + (size_t)(n0 + row) * 256 + kb + cu);
      }
      __syncthreads();
      #pragma unroll
      for (int kc = 0; kc < 4; kc++) {
        bf16x8 af0 = *(const bf16x8*)&As[(wm * 32 + lr) * 136 + kc * 32 + quad * 8];
        bf16x8 af1 = *(const bf16x8*)&As[(wm * 32 + 16 + lr) * 136 + kc * 32 + quad * 8];
        bf16x8 bf0 = *(const bf16x8*)&Bs[(wn * 32 + lr) * 136 + kc * 32 + quad * 8];
        bf16x8 bf1 = *(const bf16x8*)&Bs[(wn * 32 + 16 + lr) * 136 + kc * 32 + quad * 8];
        acc[0][0] = __builtin_amdgcn_mfma_f32_16x16x32_bf16(af0, bf0, acc[0][0], 0, 0, 0);
        acc[0][1] = __builtin_amdgcn_mfma_f32_16x16x32_bf16(af0, bf1, acc[0][1], 0, 0, 0);
        acc[1][0] = __builtin_amdgcn_mfma_f32_16x16x32_bf16(af1, bf0, acc[1][0], 0, 0, 0);
        acc[1][1] = __builtin_amdgcn_mfma_f32_16x16x32_bf16(af1, bf1, acc[1][1], 0, 0, 0);
      }
    }
    float amax = 0.f;
    #pragma unroll
    for (int mi = 0; mi < 2; mi++)
      #pragma unroll
      for (int ni = 0; ni < 2; ni++) {
        int col = n0 + wn * 32 + ni * 16 + lr;
        float bv = kvb[col];
        #pragma unroll
        for (int r = 0; r < 4; r++) {
          int row = m0 + wm * 32 + mi * 16 + quad * 4 + r;
          float v = acc[mi][ni][r] + bv;
          int b = row >> 8, n2 = row & 255;
          int h = (col >> 5) & 7, j = col & 31;
          if (col < 256)
            kqu[((size_t)((b * 8 + h) * 256 + n2)) * 32 + j] = f2bf(v);
          else
            vqtu[((size_t)((b * 8 + h) * 32 + j)) * 256 + n2] = f2bf(v);
          amax = fmaxf(amax, fabsf(v));
        }
      }
    #pragma unroll
    for (int d = 1; d < 64; d <<= 1) amax = fmaxf(amax, __shfl_xor(amax, d, 64));
    if (lane == 0) wredG[(blockIdx.x << 2) | wid] = amax;
  } else {
    // ---------------- q GEMM (XCD-swizzled 128x128) ----------------
    unsigned short* As = smem;            // 128*72
    unsigned short* Bs = smem + 9216;     // 128*72
    const int id = blockIdx.x - 256;
    const int xcd = id & 7, idx = id >> 3;          // 64 blocks per XCD
    const int mt = xcd * 32 + (idx >> 1), nt = idx & 1;
    const int m0 = mt * 128, n0 = nt * 128;
    f32x4 acc[4][4] = {};
    for (int kb = 0; kb < 256; kb += 64) {
      __syncthreads();
      #pragma unroll
      for (int i = 0; i < 4; i++) {
        int c = i * 256 + tid;
        int row = c >> 3, cu = (c & 7) * 8;
        *(uint4*)&As[row * 72 + cu] = *(const uint4*)(xb + (size_t)(m0 + row) * 256 + kb + cu);
        *(uint4*)&Bs[row * 72 + cu] = *(const uint4*)(qw + (size_t)(n0 + row) * 256 + kb + cu);
      }
      __syncthreads();
      #pragma unroll
      for (int kc = 0; kc < 2; kc++) {
        bf16x8 af[4], bf[4];
        #pragma unroll
        for (int mi = 0; mi < 4; mi++)
          af[mi] = *(const bf16x8*)&As[(wm * 64 + mi * 16 + lr) * 72 + kc * 32 + quad * 8];
        #pragma unroll
        for (int ni = 0; ni < 4; ni++)
          bf[ni] = *(const bf16x8*)&Bs[(wn * 64 + ni * 16 + lr) * 72 + kc * 32 + quad * 8];
        #pragma unroll
        for (int mi = 0; mi < 4; mi++)
          #pragma unroll
          for (int ni = 0; ni < 4; ni++)
            acc[mi][ni] = __builtin_amdgcn_mfma_f32_16x16x32_bf16(af[mi], bf[ni], acc[mi][ni], 0, 0, 0);
      }
    }
    float amax = 0.f;
    #pragma unroll
    for (int mi = 0; mi < 4; mi++)
      #pragma unroll
      for (int ni = 0; ni < 4; ni++) {
        int col = n0 + wn * 64 + ni * 16 + lr;
        float bv = qb[col];
        #pragma unroll
        for (int r = 0; r < 4; r++) {
          int row = m0 + wm * 64 + mi * 16 + quad * 4 + r;
          float v = acc[mi][ni][r] + bv;
          int b = row >> 12, nn = row & 4095;
          int h = col >> 5, j = col & 31;
          qq[((size_t)(b * 8 + h) * 4096 + nn) * 32 + j] = f2bf(v);
          amax = fmaxf(amax, fabsf(v));
        }
      }
    #pragma unroll
    for (int d = 1; d < 64; d <<= 1) amax = fmaxf(amax, __shfl_xor(amax, d, 64));
    if (lane == 0) wredG[(blockIdx.x << 2) | wid] = amax;
  }
}

// reduce wredG[3072] -> scal[4]=qmax, scal[5]=kmax, scal[6]=vmax
__global__ __launch_bounds__(256) void k_redG(const float* __restrict__ wredG, float* scal) {
  int t = threadIdx.x, wid = t >> 6, lane = t & 63;
  float mk = 0.f, mv = 0.f, mq = 0.f;
  #pragma unroll
  for (int i = 0; i < 12; i++) {
    int idx = t + i * 256;
    float v = wredG[idx];
    int bid = idx >> 2;
    if (bid < 256) {
      if ((bid & 7) < 4) mk = fmaxf(mk, v);
      else               mv = fmaxf(mv, v);
    } else {
      mq = fmaxf(mq, v);
    }
  }
  #pragma unroll
  for (int d = 1; d < 64; d <<= 1) {
    mk = fmaxf(mk, __shfl_xor(mk, d, 64));
    mv = fmaxf(mv, __shfl_xor(mv, d, 64));
    mq = fmaxf(mq, __shfl_xor(mq, d, 64));
  }
  __shared__ float red[12];
  if (lane == 0) { red[wid] = mk; red[4 + wid] = mv; red[8 + wid] = mq; }
  __syncthreads();
  if (t == 0) {
    scal[5] = fmaxf(fmaxf(red[0], red[1]), fmaxf(red[2], red[3]));
    scal[6] = fmaxf(fmaxf(red[4], red[5]), fmaxf(red[6], red[7]));
    scal[4] = fmaxf(fmaxf(red[8], red[9]), fmaxf(red[10], red[11]));
  }
}

// ---- 128x128-tile GEMM (proj): f32 C out, XCD-swizzled ----
__global__ __launch_bounds__(256) void k_gemm128(const unsigned short* __restrict__ Ab,
                                                 const unsigned short* __restrict__ W,
                                                 const float* __restrict__ bias,
                                                 float* __restrict__ C) {
  __shared__ unsigned short As[128 * 72];
  __shared__ unsigned short Bs[128 * 72];
  const int id = blockIdx.x;
  const int xcd = id & 7, idx = id >> 3;
  const int mt = xcd * 32 + (idx >> 1), nt = idx & 1;
  const int m0 = mt * 128, n0 = nt * 128;
  const int tid = threadIdx.x;
  const int wid = tid >> 6, lane = tid & 63;
  const int quad = lane >> 4, lr = lane & 15;
  const int wm = wid >> 1, wn = wid & 1;
  f32x4 acc[4][4] = {};
  for (int kb = 0; kb < 256; kb += 64) {
    __syncthreads();
    #pragma unroll
    for (int i = 0; i < 4; i++) {
      int c = i * 256 + tid;
      int row = c >> 3, cu = (c & 7) * 8;
      *(uint4*)&As[row * 72 + cu] = *(const uint4*)(Ab + (size_t)(m0 + row) * 256 + kb + cu);
      *(uint4*)&Bs[row * 72 + cu] = *(const uint4*)(W + (size_t)(n0 + row) * 256 + kb + cu);
    }
    __syncthreads();
    #pragma unroll
    for (int kc = 0; kc < 2; kc++) {
      bf16x8 af[4], bf[4];
      #pragma unroll
      for (int mi = 0; mi < 4; mi++)
        af[mi] = *(const bf16x8*)&As[(wm * 64 + mi * 16 + lr) * 72 + kc * 32 + quad * 8];
      #pragma unroll
      for (int ni = 0; ni < 4; ni++)
        bf[ni] = *(const bf16x8*)&Bs[(wn * 64 + ni * 16 + lr) * 72 + kc * 32 + quad * 8];
      #pragma unroll
      for (int mi = 0; mi < 4; mi++)
        #pragma unroll
        for (int ni = 0; ni < 4; ni++)
          acc[mi][ni] = __builtin_amdgcn_mfma_f32_16x16x32_bf16(af[mi], bf[ni], acc[mi][ni], 0, 0, 0);
    }
  }
  #pragma unroll
  for (int mi = 0; mi < 4; mi++)
    #pragma unroll
    for (int ni = 0; ni < 4; ni++) {
      int col = n0 + wn * 64 + ni * 16 + lr;
      float bv = bias[col];
      #pragma unroll
      for (int r = 0; r < 4; r++) {
        int row = m0 + wm * 64 + mi * 16 + quad * 4 + r;
        C[(size_t)row * 256 + col] = acc[mi][ni][r] + bv;
      }
    }
}

// ---- conv GEMM: 2048x256xK4096, split-K=4, im2col fused (bf16 x); flat grid 512
__global__ __launch_bounds__(256) void k_conv_sk(const unsigned short* __restrict__ xb,
                                                 const unsigned short* __restrict__ W,
                                                 float* __restrict__ C) {
  __shared__ unsigned short As[64 * 136];
  __shared__ unsigned short Bs[64 * 136];
  const int id = blockIdx.x;
  const int xcd = id & 7, idx = id >> 3;
  const int a = idx >> 2, nt = idx & 3;
  const int ag = xcd * 16 + a;
  const int mt = ag & 31, z = ag >> 5;
  const int m0 = mt * 64, n0 = nt * 64;
  const int kOff = z * 1024;
  C += (size_t)z * 2048 * 256;
  const int tid = threadIdx.x;
  const int wid = tid >> 6, lane = tid & 63;
  const int quad = lane >> 4, lr = lane & 15;
  const int wm = wid >> 1, wn = wid & 1;
  f32x4 acc[2][2] = {};
  for (int kb = 0; kb < 1024; kb += 128) {
    __syncthreads();
    #pragma unroll
    for (int i = 0; i < 4; i++) {
      int c = i * 256 + tid;
      int row = c >> 4, cu = (c & 15) * 8;
      int kk = kOff + kb + cu;
      int m = m0 + row;
      int b = m >> 8, p = m & 255, ph = p >> 4, pw = p & 15;
      int q = kk >> 8, ii = kk & 255;
      int n = (ph * 4 + (q >> 2)) * 64 + pw * 4 + (q & 3);
      *(uint4*)&As[row * 136 + cu] = *(const uint4*)(xb + ((size_t)(b * 4096 + n) * 256 + ii));
      *(uint4*)&Bs[row * 136 + cu] = *(const uint4*)(W + (size_t)(n0 + row) * 4096 + kk);
    }
    __syncthreads();
    #pragma unroll
    for (int kc = 0; kc < 4; kc++) {
      bf16x8 af0 = *(const bf16x8*)&As[(wm * 32 + lr) * 136 + kc * 32 + quad * 8];
      bf16x8 af1 = *(const bf16x8*)&As[(wm * 32 + 16 + lr) * 136 + kc * 32 + quad * 8];
      bf16x8 bf0 = *(const bf16x8*)&Bs[(wn * 32 + lr) * 136 + kc * 32 + quad * 8];
      bf16x8 bf1 = *(const bf16x8*)&Bs[(wn * 32 + 16 + lr) * 136 + kc * 32 + quad * 8];
      acc[0][0] = __builtin_amdgcn_mfma_f32_16x16x32_bf16(af0, bf0, acc[0][0], 0, 0, 0);
      acc[0][1] = __builtin_amdgcn_mfma_f32_16x16x32_bf16(af0, bf1, acc[0][1], 0, 0, 0);
      acc[1][0] = __builtin_amdgcn_mfma_f32_16x16x32_bf16(af1, bf0, acc[1][0], 0, 0, 0);
      acc[1][1] = __builtin_amdgcn_mfma_f32_16x16x32_bf16(af1, bf1, acc[1][1], 0, 0, 0);
    }
  }
  #pragma unroll
  for (int mi = 0; mi < 2; mi++)
    #pragma unroll
    for (int ni = 0; ni < 2; ni++) {
      int col = n0 + wn * 32 + ni * 16 + lr;
      #pragma unroll
      for (int r = 0; r < 4; r++) {
        int row = m0 + wm * 32 + mi * 16 + quad * 4 + r;
        C[(size_t)row * 256 + col] = acc[mi][ni][r];
      }
    }
}

// LayerNorm over C=256; sums 4 split-K conv partials + sr_b first
__global__ __launch_bounds__(256) void k_ln(const float* __restrict__ convp, const float* srb,
                                            const float* g, const float* bb,
                                            unsigned short* __restrict__ xn) {
  int row = blockIdx.x, c = threadIdx.x;
  float v = srb[c];
  #pragma unroll
  for (int s = 0; s < 4; s++) v += convp[s * 524288 + row * 256 + c];
  __shared__ float red[4];
  float s = v;
  #pragma unroll
  for (int d = 1; d < 64; d <<= 1) s += __shfl_xor(s, d, 64);
  if ((c & 63) == 0) red[c >> 6] = s;
  __syncthreads();
  float mu = (red[0] + red[1] + red[2] + red[3]) * (1.f / 256.f);
  __syncthreads();
  float dv = v - mu;
  float s2 = dv * dv;
  #pragma unroll
  for (int d = 1; d < 64; d <<= 1) s2 += __shfl_xor(s2, d, 64);
  if ((c & 63) == 0) red[c >> 6] = s2;
  __syncthreads();
  float var = (red[0] + red[1] + red[2] + red[3]) * (1.f / 256.f);
  float rs = 1.f / sqrtf(var + 1e-5f);
  xn[row * 256 + c] = f2bf(dv * rs * g[c] + bb[c]);
}

// attention pass 1 (R16): swapped QK^T; K staged lane-major + fake-quant in
// staging; q quantized in-register. Per-block (wmin,wmax) -> pstat (no atomics).
// Grid 32x64 (2 row-groups/block) for 8 blocks/CU latency hiding.
__global__ __launch_bounds__(256) void k_attn1(const unsigned short* __restrict__ qq,
                                               const unsigned short* __restrict__ kqu,
                                               float2* __restrict__ rowstats,
                                               const float* __restrict__ scal,
                                               float2* __restrict__ pstat) {
  __shared__ unsigned short KsL[8192];  // 16 KB: [t(16)][lane(64)] x 8 shorts
  __shared__ float red[8];
  const int bh = blockIdx.y;
  const int row0 = blockIdx.x * 128;
  const int tid = threadIdx.x, wid = tid >> 6, lane = tid & 63, quad = lane >> 4, lr = lane & 15;
  const float c2 = 0.17677669529663687f * 1.4426950408889634f;  // 32^-0.5 * log2(e)
  const unsigned short* kb = kqu + (size_t)bh * 8192;
  float dk = scal[5] / 127.f + 1e-8f;
  float idk = 1.f / dk;
  float dq = scal[4] / 127.f + 1e-8f;
  float idq = 1.f / dq;
  #pragma unroll
  for (int k = 0; k < 4; k++) {
    int cid = k * 256 + tid;                 // 1024 chunks of 16B
    int seg = cid >> 6, lc = cid & 63, qc = lc >> 4, lrc = lc & 15;
    uint4 kw = *(const uint4*)(kb + (seg * 16 + lrc) * 32 + qc * 8);
    *(uint4*)&KsL[cid * 8] = qfrag4(kw, idk, dk);
  }
  __syncthreads();
  float wmin = 1e30f, wmax = 0.f;
  #pragma unroll
  for (int g = 0; g < 2; g++) {
    int rowg = row0 + g * 64 + wid * 16 + lr;
    uint4 qw = *(const uint4*)(qq + ((size_t)bh * 4096 + rowg) * 32 + quad * 8);
    bf16x8 qf = qfrag(qw, idq, dq);
    f32x4 acc[16] = {};
    #pragma unroll
    for (int t = 0; t < 16; t++) {
      bf16x8 kf = *(const bf16x8*)&KsL[(t * 64 + quad * 16 + lr) * 8];
      acc[t] = __builtin_amdgcn_mfma_f32_16x16x32_bf16(kf, qf, acc[t], 0, 0, 0);
    }
    float mxr = -1e30f, mnr = 1e30f;
    #pragma unroll
    for (int t = 0; t < 16; t++)
      #pragma unroll
      for (int r = 0; r < 4; r++) {
        float s = acc[t][r];
        mxr = fmaxf(mxr, s); mnr = fminf(mnr, s);
      }
    #pragma unroll
    for (int d = 16; d < 64; d <<= 1) {
      mxr = fmaxf(mxr, __shfl_xor(mxr, d, 64));
      mnr = fminf(mnr, __shfl_xor(mnr, d, 64));
    }
    float m2 = mxr * c2;
    float l = 0.f;
    #pragma unroll
    for (int t = 0; t < 16; t++)
      #pragma unroll
      for (int r = 0; r < 4; r++)
        l += exp2_(fmaf(acc[t][r], c2, -m2));
    #pragma unroll
    for (int d = 16; d < 64; d <<= 1) l += __shfl_xor(l, d, 64);
    float inv_l = 1.f / l;
    if (lane < 16)
      rowstats[(size_t)bh * 4096 + rowg] = make_float2(m2, inv_l);
    wmax = fmaxf(wmax, inv_l);
    wmin = fminf(wmin, exp2_((mnr - mxr) * c2) * inv_l);
  }
  #pragma unroll
  for (int d = 1; d < 16; d <<= 1) {
    wmax = fmaxf(wmax, __shfl_xor(wmax, d, 64));
    wmin = fminf(wmin, __shfl_xor(wmin, d, 64));
  }
  if (lane == 0) { red[wid] = wmin; red[4 + wid] = wmax; }
  __syncthreads();
  if (tid == 0) {
    float mn = fminf(fminf(red[0], red[1]), fminf(red[2], red[3]));
    float mx = fmaxf(fmaxf(red[4], red[5]), fmaxf(red[6], red[7]));
    pstat[blockIdx.y * 32 + blockIdx.x] = make_float2(mn, mx);
  }
}

// reduce pstat[2048] -> scal[7]=pmin, scal[8]=pmax  (single block)
__global__ __launch_bounds__(256) void k_pminmax(const float2* __restrict__ pstat, float* scal) {
  int t = threadIdx.x;
  float mn = 1e30f, mx = 0.f;
  #pragma unroll
  for (int i = 0; i < 8; i++) {
    float2 v = pstat[t + i * 256];
    mn = fminf(mn, v.x); mx = fmaxf(mx, v.y);
  }
  #pragma unroll
  for (int d = 1; d < 64; d <<= 1) {
    mn = fminf(mn, __shfl_xor(mn, d, 64));
    mx = fmaxf(mx, __shfl_xor(mx, d, 64));
  }
  __shared__ float red[8];
  if ((t & 63) == 0) { red[t >> 6] = mn; red[4 + (t >> 6)] = mx; }
  __syncthreads();
  if (t == 0) {
    scal[7] = fminf(fminf(red[0], red[1]), fminf(red[2], red[3]));
    scal[8] = fmaxf(fmaxf(red[4], red[5]), fmaxf(red[6], red[7]));
  }
}

// attention pass 2: swapped-QK in-register softmax/quant; K/V staged lane-major
// with fake-quant in staging; q quantized on load.
__global__ __launch_bounds__(256) void k_attn2(const unsigned short* __restrict__ qq,
                                               const unsigned short* __restrict__ kqu,
                                               const unsigned short* __restrict__ vqtu,
                                               const float* __restrict__ scal,
                                               const float2* __restrict__ rowstats,
                                               unsigned short* __restrict__ attn_out) {
  __shared__ unsigned short KsL[8192];  // 16 KB: [t(16)][lane(64)] chunks
  __shared__ unsigned short VsL[8192];  // 16 KB: [ks*2+half(16)][lane(64)] chunks
  const int bh = blockIdx.y, b = bh >> 3, h = bh & 7;
  const int row0 = blockIdx.x * 256;
  const int tid = threadIdx.x, wid = tid >> 6, lane = tid & 63, quad = lane >> 4, lr = lane & 15;
  const float c2 = 0.17677669529663687f * 1.4426950408889634f;
  const unsigned short* kb = kqu + (size_t)bh * 8192;
  const unsigned short* vb = vqtu + (size_t)bh * 8192;
  float dk = scal[5] / 127.f + 1e-8f;
  float idk = 1.f / dk;
  float dv = scal[6] / 127.f + 1e-8f;
  float idv = 1.f / dv;
  float dq = scal[4] / 127.f + 1e-8f;
  float idq = 1.f / dq;
  #pragma unroll
  for (int k = 0; k < 4; k++) {
    int cid = k * 256 + tid;
    int seg = cid >> 6, lc = cid & 63, qc = lc >> 4, lrc = lc & 15;
    uint4 kw = *(const uint4*)(kb + (seg * 16 + lrc) * 32 + qc * 8);
    *(uint4*)&KsL[cid * 8] = qfrag4(kw, idk, dk);
    uint4 vw = *(const uint4*)(vb + ((seg & 1) * 16 + lrc) * 256 + (seg >> 1) * 32 + qc * 8);
    *(uint4*)&VsL[cid * 8] = qfrag4(vw, idv, dv);
  }
  float pmin = scal[7], pmax = scal[8];
  float delta = (pmax - pmin) / 255.f + 1e-8f;
  float zp = rintf(-pmin / delta);
  float qlo = -zp, qhi = 255.f - zp;
  __syncthreads();
  #pragma unroll
  for (int g = 0; g < 4; g++) {
    int rowg = row0 + g * 64 + wid * 16 + lr;
    uint4 qw = *(const uint4*)(qq + ((size_t)bh * 4096 + rowg) * 32 + quad * 8);
    bf16x8 qf = qfrag(qw, idq, dq);
    float2 st = rowstats[(size_t)bh * 4096 + rowg];
    f32x4 acc[16] = {};
    #pragma unroll
    for (int t = 0; t < 16; t++) {
      bf16x8 kf = *(const bf16x8*)&KsL[(t * 64 + quad * 16 + lr) * 8];
      acc[t] = __builtin_amdgcn_mfma_f32_16x16x32_bf16(kf, qf, acc[t], 0, 0, 0);
    }
    float ofs = __log2f(st.y / delta) - st.x;
    f32x4 o0 = {}, o1 = {};
    #pragma unroll
    for (int ks = 0; ks < 8; ks++) {
      float pv[8];
      #pragma unroll
      for (int half = 0; half < 2; half++) {
        #pragma unroll
        for (int r = 0; r < 4; r++) {
          float v = exp2_(fmaf(acc[2 * ks + half][r], c2, ofs));
          pv[half * 4 + r] = fminf(fmaxf(rintf(v), qlo), qhi) * delta;
        }
      }
      unsigned wa = cvtpk(pv[0], pv[1]);
      unsigned wb = cvtpk(pv[2], pv[3]);
      unsigned wc = cvtpk(pv[4], pv[5]);
      unsigned wd = cvtpk(pv[6], pv[7]);
      pl32swap(wa, wc);
      pl16swap(wa, wc);
      pl32swap(wb, wd);
      pl16swap(wb, wd);
      uint4 w = make_uint4(wa, wb, wc, wd);
      bf16x8 pa = *(bf16x8*)&w;
      bf16x8 b0 = *(const bf16x8*)&VsL[((ks * 2 + 0) * 64 + quad * 16 + lr) * 8];
      bf16x8 b1 = *(const bf16x8*)&VsL[((ks * 2 + 1) * 64 + quad * 16 + lr) * 8];
      o0 = __builtin_amdgcn_mfma_f32_16x16x32_bf16(pa, b0, o0, 0, 0, 0);
      o1 = __builtin_amdgcn_mfma_f32_16x16x32_bf16(pa, b1, o1, 0, 0, 0);
    }
    #pragma unroll
    for (int r = 0; r < 4; r++) {
      int n = row0 + g * 64 + wid * 16 + quad * 4 + r;
      size_t base = ((size_t)(b * 4096) + n) * 256 + h * 32;
      attn_out[base + lr] = f2bf(o0[r]);
      attn_out[base + 16 + lr] = f2bf(o1[r]);
    }
  }
}

extern "C" void kernel_launch(void* const* d_in, const int* in_sizes, int n_in,
                              void* d_out, int out_size, void* d_ws, size_t ws_size,
                              hipStream_t stream) {
  const float* x      = (const float*)d_in[0];
  const float* q_w    = (const float*)d_in[1];
  const float* q_b    = (const float*)d_in[2];
  const float* kv_w   = (const float*)d_in[3];
  const float* kv_b   = (const float*)d_in[4];
  const float* sr_w   = (const float*)d_in[5];
  const float* sr_b   = (const float*)d_in[6];
  const float* norm_g = (const float*)d_in[7];
  const float* norm_b = (const float*)d_in[8];
  const float* proj_w = (const float*)d_in[9];
  const float* proj_b = (const float*)d_in[10];
  float* out = (float*)d_out;

  char* ws = (char*)d_ws;
  float* scal = (float*)ws;
  unsigned short* q_wq    = (unsigned short*)(ws + 256);       // 128 KB
  unsigned short* kv_wq   = (unsigned short*)(ws + 131328);    // 256 KB
  unsigned short* proj_wq = (unsigned short*)(ws + 393472);    // 128 KB
  unsigned short* sr_wq   = (unsigned short*)(ws + 524544);    // 2 MB   -> 2621696
  unsigned short* xn      = (unsigned short*)(ws + 2621696);   // 1 MB   -> 3670272
  unsigned short* kqu     = (unsigned short*)(ws + 7864576);   // 1 MB (bf16 k, UNquantized)
  unsigned short* vqtu    = (unsigned short*)(ws + 8913152);   // 1 MB (bf16 v^T, UNquantized)
  float2*         rowstats= (float2*)(ws + 9961728);           // 2 MB   -> 12058880
  float*          convp   = (float*)(ws + 12058880);           // 8 MB (4 partials)
  unsigned short* attn_o  = (unsigned short*)(ws + 12058880);  // over convp (dead after k_ln); 16 MB
  float2*         pstat   = (float2*)(ws + 28836096);          // 16 KB
  unsigned short* qq      = (unsigned short*)(ws + 45613312);  // 16 MB (bf16 q, UNquantized)
  unsigned short* xb      = (unsigned short*)(ws + 62390528);  // 16 MB (x as bf16) -> 79167744
  float*          wredW   = (float*)(ws + 79167744);           // 1 KB (absmax partials)
  float*          wredG   = (float*)(ws + 79168768);           // 12 KB (gemm amax partials)

  k_absmax4<<<dim3(64, 4), 256, 0, stream>>>(q_w, kv_w, sr_w, proj_w, wredW);
  k_redW<<<1, 256, 0, stream>>>(wredW, scal);
  // weight quant + x->bf16 cast
  k_quantw<<<4096, 256, 0, stream>>>(q_w, kv_w, proj_w, sr_w, x,
                                     q_wq, kv_wq, proj_wq, sr_wq, xb, scal);
  // conv GEMM (im2col fused, split-K=4, XCD-swizzled): 2048x256x4096
  k_conv_sk<<<512, 256, 0, stream>>>(xb, sr_wq, convp);
  k_ln<<<2048, 256, 0, stream>>>(convp, sr_b, norm_g, norm_b, xn);
  // FUSED kv-GEMM (256 blocks) + q-GEMM (512 blocks); per-wave amax -> wredG
  k_gemm_qkv<<<768, 256, 0, stream>>>(xn, kv_wq, kv_b, xb, q_wq, q_b,
                                      kqu, vqtu, qq, wredG);
  k_redG<<<1, 256, 0, stream>>>(wredG, scal);
  k_attn1<<<dim3(32, 64), 256, 0, stream>>>(qq, kqu, rowstats, scal, pstat);
  k_pminmax<<<1, 256, 0, stream>>>(pstat, scal);
  k_attn2<<<dim3(16, 64), 256, 0, stream>>>(qq, kqu, vqtu, scal, rowstats, attn_o);
  // proj GEMM: 32768x256x256, 128-tile, XCD-swizzled
  k_gemm128<<<512, 256, 0, stream>>>(attn_o, proj_wq, proj_b, out);
}